// Round 9
// baseline (191.074 us; speedup 1.0000x reference)
//
#include <hip/hip_runtime.h>
#include <hip/hip_fp16.h>
#include <math.h>

#define BINSN 50
#define DD 32
#define DD4 8
#define BWF 0.02f            // fp32 of LAST_TIME/BINS
#define EPSF 1e-6f
#define SQRTPI_HALF 0.8862269254527580f
#define TS2 32               // node tile size for integral path
#define NSLOT 256
#define SLOT_STRIDE 16       // floats; 64B apart -> no contention

// Branch-free erf, Abramowitz-Stegun 7.1.26, |err| <= 1.5e-7 absolute.
__device__ __forceinline__ float fast_erff(float x) {
  float ax = fabsf(x);
  float t = __fdividef(1.0f, fmaf(0.3275911f, ax, 1.0f));
  float p = t * fmaf(t, fmaf(t, fmaf(t, fmaf(t, 1.061405429f, -1.453152027f),
                                     1.421413741f), -0.284496736f), 0.254829592f);
  float y = 1.0f - p * __expf(-ax * ax);
  return copysignf(y, x);
}

__device__ __forceinline__ void block_reduce_to_slot(float acc, float* slots) {
#pragma unroll
  for (int m = 32; m >= 1; m >>= 1) acc += __shfl_xor(acc, m, 64);
  __shared__ float red[4];
  int wid = threadIdx.x >> 6;
  if ((threadIdx.x & 63) == 0) red[wid] = acc;
  __syncthreads();
  if (threadIdx.x == 0) {
    float tot = red[0] + red[1] + red[2] + red[3];
    atomicAdd(&slots[(blockIdx.x & (NSLOT - 1)) * SLOT_STRIDE], tot);
  }
}

// ---------------- Kernel 1: fused {pos->fp16 Ph} + {subset Ps/Vs/Bs} -----------
// blocks [0, posBlocks): Ph[b,n,d] = half(x0 + BW*cumsum(v)), 2 dims/thread.
// blocks [posBlocks, posBlocks+subBlocks): one thread per (s,d), serial over
// bins, carrying the f32 running cumsum (non-redundant).
__global__ __launch_bounds__(256)
void prep_kernel(const float2* __restrict__ x02, const float2* __restrict__ v2,
                 __half2* __restrict__ Ph2, int ND2,
                 const float* __restrict__ x0, const float* __restrict__ v,
                 const float* __restrict__ beta, const int* __restrict__ nodes,
                 float* __restrict__ Ps, float* __restrict__ Vs,
                 float* __restrict__ Bs,
                 int N, int S, int posBlocks,
                 float* __restrict__ slots) {
  int tx = threadIdx.x;
  if (blockIdx.x == 0) {
    for (int o = tx; o < NSLOT * SLOT_STRIDE; o += blockDim.x) slots[o] = 0.f;
  }
  if ((int)blockIdx.x < posBlocks) {
    int idx = blockIdx.x * blockDim.x + tx;
    if (idx >= ND2) return;
    float2 run = x02[idx];
#pragma unroll 10
    for (int b = 0; b < BINSN; ++b) {
      size_t off = (size_t)b * ND2 + idx;
      Ph2[off] = __floats2half2_rn(run.x, run.y);
      float2 vv = v2[off];
      run.x = fmaf(BWF, vv.x, run.x);
      run.y = fmaf(BWF, vv.y, run.y);
    }
  } else {
    const int ND = N * DD;
    int flat = (blockIdx.x - posBlocks) * blockDim.x + tx;  // (s,d)
    if (flat >= S * DD) return;
    int d = flat & (DD - 1);
    int s = flat >> 5;
    int node = nodes[s];
    size_t base = (size_t)node * DD + d;
    float run = x0[base];
    if (d == 0) Bs[s] = beta[node];
#pragma unroll 10
    for (int b = 0; b < BINSN; ++b) {
      size_t so = ((size_t)b * S + s) * DD + d;
      float vv = v[(size_t)b * ND + base];
      Ps[so] = run;
      Vs[so] = vv;
      run = fmaf(BWF, vv, run);
    }
  }
}

// ---------------- Kernel 2: -sum(log_intensity), ONE event per 32-lane slot ----
__global__ __launch_bounds__(256)
void event_kernel_h(const __half* __restrict__ Ph,
                    const float* __restrict__ v,
                    const float* __restrict__ beta,
                    const float* __restrict__ times,
                    const int* __restrict__ pairs,
                    int N, int E, float* __restrict__ slots) {
  const int ND = N * DD;
  const int lane = threadIdx.x & 31;
  int e = (int)((blockIdx.x * blockDim.x + threadIdx.x) >> 5);
  float acc = 0.f;
  if (e < E) {
    float t = times[e];
    int p0 = pairs[e];
    int p1 = pairs[E + e];
    float fb = floorf(t / BWF);
    float res = fmaf(-BWF, fb, t);
    int b = (int)fb;
    b = b < 0 ? 0 : (b > BINSN - 1 ? BINSN - 1 : b);
    size_t o0 = (size_t)p0 * DD + lane;
    size_t o1 = (size_t)p1 * DD + lane;
    size_t bo = (size_t)b * ND;
    float dP = __half2float(Ph[bo + o0]) - __half2float(Ph[bo + o1]);
    float dx = dP + res * (v[bo + o0] - v[bo + o1]);
    float s = dx * dx;
#pragma unroll
    for (int m = 16; m >= 1; m >>= 1) s += __shfl_xor(s, m, 64);
    if (lane == 0) acc = s - beta[p0] - beta[p1];
  }
  block_reduce_to_slot(acc, slots);
}

// ---------------- Kernel 3: survival integral, one (32x32 tile, bin) per block --
// Dense L2/L3-resident Ps/Vs/Bs; one sync; fully scalarized; slot sink only.
// __launch_bounds__(256,4): cap VGPR at 128 -> 4 blocks/CU (was 168 VGPR = 2).
__global__ __launch_bounds__(256, 4)
void integral_v8(const float4* __restrict__ Ps4,
                 const float4* __restrict__ Vs4,
                 const float* __restrict__ Bs,
                 int S, int nTileRows, int nTiles,
                 float* __restrict__ slots) {
  int tile = blockIdx.x % nTiles;
  int b = blockIdx.x / nTiles;
  int ti = 0;
  {
    int rem = tile;
    while (rem >= nTileRows - ti) { rem -= (nTileRows - ti); ++ti; }
    tile = rem;
  }
  int tj = ti + tile;

  __shared__ float sP[64][36];   // pad 36: strided j-reads -> free 2-way conflict
  __shared__ float sV[64][36];
  __shared__ float sB[64];

  int tx = threadIdx.x;
  {
    int row = tx >> 3, q = tx & 7;
    int g0 = ti * TS2 + row;
    if (g0 >= S) g0 = S - 1;
    size_t a0 = ((size_t)b * S + g0) * DD4 + q;
    *(float4*)&sP[row][q * 4] = Ps4[a0];
    *(float4*)&sV[row][q * 4] = Vs4[a0];
    int g1 = tj * TS2 + row;
    if (g1 >= S) g1 = S - 1;
    size_t a1 = ((size_t)b * S + g1) * DD4 + q;
    *(float4*)&sP[row + 32][q * 4] = Ps4[a1];
    *(float4*)&sV[row + 32][q * 4] = Vs4[a1];
    if (q == 0) { sB[row] = Bs[g0]; sB[row + 32] = Bs[g1]; }
  }
  __syncthreads();

  int ii = tx >> 4;
  int jj = tx & 15;

  float sdd00 = 0.f, sxd00 = 0.f, sxx00 = 0.f;
  float sdd01 = 0.f, sxd01 = 0.f, sxx01 = 0.f;
  float sdd10 = 0.f, sxd10 = 0.f, sxx10 = 0.f;
  float sdd11 = 0.f, sxd11 = 0.f, sxx11 = 0.f;

#define CELL(SDD, SXD, SXX, PA, PB, VA, VB)                                    \
  {                                                                            \
    float dx0 = PA.x - PB.x, dx1 = PA.y - PB.y;                                \
    float dx2 = PA.z - PB.z, dx3 = PA.w - PB.w;                                \
    float dv0 = VA.x - VB.x, dv1 = VA.y - VB.y;                                \
    float dv2 = VA.z - VB.z, dv3 = VA.w - VB.w;                                \
    SDD = fmaf(dv0, dv0, fmaf(dv1, dv1, fmaf(dv2, dv2, fmaf(dv3, dv3, SDD)))); \
    SXD = fmaf(dx0, dv0, fmaf(dx1, dv1, fmaf(dx2, dv2, fmaf(dx3, dv3, SXD)))); \
    SXX = fmaf(dx0, dx0, fmaf(dx1, dx1, fmaf(dx2, dx2, fmaf(dx3, dx3, SXX)))); \
  }

#pragma unroll
  for (int q = 0; q < 8; ++q) {
    const float4 Pi0 = *(const float4*)&sP[ii][q * 4];
    const float4 Pi1 = *(const float4*)&sP[ii + 16][q * 4];
    const float4 Pj0 = *(const float4*)&sP[TS2 + jj][q * 4];
    const float4 Pj1 = *(const float4*)&sP[TS2 + jj + 16][q * 4];
    const float4 Vi0 = *(const float4*)&sV[ii][q * 4];
    const float4 Vi1 = *(const float4*)&sV[ii + 16][q * 4];
    const float4 Vj0 = *(const float4*)&sV[TS2 + jj][q * 4];
    const float4 Vj1 = *(const float4*)&sV[TS2 + jj + 16][q * 4];
    CELL(sdd00, sxd00, sxx00, Pi0, Pj0, Vi0, Vj0);
    CELL(sdd01, sxd01, sxx01, Pi0, Pj1, Vi0, Vj1);
    CELL(sdd10, sxd10, sxx10, Pi1, Pj0, Vi1, Vj0);
    CELL(sdd11, sxd11, sxx11, Pi1, Pj1, Vi1, Vj1);
  }
#undef CELL

  float acc = 0.f;
  const float tlo = (float)b * BWF;
  const float thi = (float)(b + 1) * BWF;

#define FIN(SDD, SXD, SXX, AOFF, COFF)                                         \
  {                                                                            \
    int li = ii + (AOFF), lj = jj + (COFF);                                    \
    int gi = ti * TS2 + li, gj = tj * TS2 + lj;                                \
    if (gi < gj && gj < S) {                                                   \
      float ndv = sqrtf(SDD);                                                  \
      float inv = __fdividef(1.0f, ndv + EPSF);                                \
      float r = SXD * inv;                                                     \
      float bij = sB[li] + sB[TS2 + lj];                                       \
      float t1 = __expf(bij + fmaf(r, r, -(SXX)));                             \
      float lo = fmaf(tlo, ndv, r);                                            \
      float hi = fmaf(thi, ndv, r);                                            \
      acc += SQRTPI_HALF * inv * t1 * (fast_erff(hi) - fast_erff(lo));         \
    }                                                                          \
  }

  FIN(sdd00, sxd00, sxx00, 0, 0);
  FIN(sdd01, sxd01, sxx01, 0, 16);
  FIN(sdd10, sxd10, sxx10, 16, 0);
  FIN(sdd11, sxd11, sxx11, 16, 16);
#undef FIN

  block_reduce_to_slot(acc, slots);
}

// ---------------- finalize: sum slots -> out[0] ----------------
__global__ void finalize_kernel(const float* __restrict__ slots,
                                float* __restrict__ out, int out_size) {
  float a = slots[threadIdx.x * SLOT_STRIDE];
#pragma unroll
  for (int m = 32; m >= 1; m >>= 1) a += __shfl_xor(a, m, 64);
  __shared__ float red[4];
  int wid = threadIdx.x >> 6;
  if ((threadIdx.x & 63) == 0) red[wid] = a;
  __syncthreads();
  if (threadIdx.x == 0) out[0] = red[0] + red[1] + red[2] + red[3];
  if (threadIdx.x > 0 && threadIdx.x < out_size) out[threadIdx.x] = 0.f;
}

// ---------------- Fallback kernels (workspace too small) ----------------
__global__ void event_kernel_fb(const float* __restrict__ x0,
                                const float* __restrict__ v,
                                const float* __restrict__ beta,
                                const float* __restrict__ times,
                                const int* __restrict__ pairs,
                                int N, int E, float* __restrict__ out) {
  const int ND = N * DD;
  const int lane = threadIdx.x & 31;
  int slot = (blockIdx.x * blockDim.x + threadIdx.x) >> 5;
  const int nslots = (gridDim.x * blockDim.x) >> 5;
  float acc = 0.f;
  for (int e = slot; e < E; e += nslots) {
    float t = times[e];
    int p0 = pairs[e];
    int p1 = pairs[E + e];
    float fb = floorf(t / BWF);
    float res = fmaf(-BWF, fb, t);
    int b = (int)fb;
    b = b < 0 ? 0 : (b > BINSN - 1 ? BINSN - 1 : b);
    size_t o0 = (size_t)p0 * DD + lane;
    size_t o1 = (size_t)p1 * DD + lane;
    size_t bo = (size_t)b * ND;
    float c0 = 0.f, c1 = 0.f;
    for (int k = 0; k < b; ++k) {
      size_t ko = (size_t)k * ND;
      c0 += v[ko + o0];
      c1 += v[ko + o1];
    }
    float dx = (x0[o0] - x0[o1]) + BWF * (c0 - c1) + res * (v[bo + o0] - v[bo + o1]);
    float s = dx * dx;
#pragma unroll
    for (int m = 16; m >= 1; m >>= 1) s += __shfl_xor(s, m, 64);
    if (lane == 0) acc += s - beta[p0] - beta[p1];
  }
#pragma unroll
  for (int m = 32; m >= 1; m >>= 1) acc += __shfl_xor(acc, m, 64);
  __shared__ float smem[16];
  int wid = threadIdx.x >> 6;
  if ((threadIdx.x & 63) == 0) smem[wid] = acc;
  __syncthreads();
  if (threadIdx.x == 0) {
    float tot = 0.f;
    int nw = blockDim.x >> 6;
    for (int w = 0; w < nw; ++w) tot += smem[w];
    atomicAdd(out, tot);
  }
}

__global__ void integral_fb(const float4* __restrict__ x04,
                            const float4* __restrict__ v4,
                            const float* __restrict__ beta,
                            const int* __restrict__ nodes,
                            int N, int S, int npair, int nPairChunks,
                            float* __restrict__ out) {
  const int nd4 = N * DD4;
  int p = (blockIdx.x % nPairChunks) * blockDim.x + threadIdx.x;
  float acc = 0.f;
  if (p < npair) {
    const int twoSm1 = 2 * S - 1;
    int i = (int)((twoSm1 - sqrt((double)twoSm1 * twoSm1 - 8.0 * (double)p)) * 0.5);
    if (i < 0) i = 0;
    if (i > S - 2) i = S - 2;
#define BASE(ii) ((ii) * (twoSm1 - (ii)) / 2)
    while (i < S - 2 && BASE(i + 1) <= p) ++i;
    while (i > 0 && BASE(i) > p) --i;
    int j = i + 1 + (p - BASE(i));
#undef BASE
    int u0 = nodes[i], u1 = nodes[j];
    float bij = beta[u0] + beta[u1];
    size_t r0 = (size_t)u0 * DD4;
    size_t r1 = (size_t)u1 * DD4;
    float dxt[DD];
#pragma unroll
    for (int q = 0; q < DD4; ++q) {
      float4 a = x04[r0 + q];
      float4 bb = x04[r1 + q];
      dxt[q * 4 + 0] = a.x - bb.x;
      dxt[q * 4 + 1] = a.y - bb.y;
      dxt[q * 4 + 2] = a.z - bb.z;
      dxt[q * 4 + 3] = a.w - bb.w;
    }
    for (int b = 0; b < BINSN; ++b) {
      size_t bo4 = (size_t)b * nd4;
      float sdd = 0.f, sxd = 0.f, sxx = 0.f;
#pragma unroll
      for (int q = 0; q < DD4; ++q) {
        float4 a = v4[bo4 + r0 + q];
        float4 c = v4[bo4 + r1 + q];
        float d0 = a.x - c.x, d1 = a.y - c.y, d2 = a.z - c.z, d3 = a.w - c.w;
        float y0 = dxt[q * 4 + 0], y1 = dxt[q * 4 + 1];
        float y2 = dxt[q * 4 + 2], y3 = dxt[q * 4 + 3];
        sdd += d0 * d0 + d1 * d1 + d2 * d2 + d3 * d3;
        sxd += y0 * d0 + y1 * d1 + y2 * d2 + y3 * d3;
        sxx += y0 * y0 + y1 * y1 + y2 * y2 + y3 * y3;
        dxt[q * 4 + 0] = fmaf(BWF, d0, y0);
        dxt[q * 4 + 1] = fmaf(BWF, d1, y1);
        dxt[q * 4 + 2] = fmaf(BWF, d2, y2);
        dxt[q * 4 + 3] = fmaf(BWF, d3, y3);
      }
      float ndv = sqrtf(sdd);
      float inv = __fdividef(1.0f, ndv + EPSF);
      float r = sxd * inv;
      float t1 = __expf(bij + r * r - sxx);
      float lo = fmaf((float)b * BWF, ndv, r);
      float hi = fmaf((float)(b + 1) * BWF, ndv, r);
      acc += SQRTPI_HALF * inv * t1 * (fast_erff(hi) - fast_erff(lo));
    }
  }
#pragma unroll
  for (int m = 32; m >= 1; m >>= 1) acc += __shfl_xor(acc, m, 64);
  __shared__ float smem[16];
  int wid = threadIdx.x >> 6;
  if ((threadIdx.x & 63) == 0) smem[wid] = acc;
  __syncthreads();
  if (threadIdx.x == 0) {
    float tot = 0.f;
    int nw = blockDim.x >> 6;
    for (int w = 0; w < nw; ++w) tot += smem[w];
    atomicAdd(out, tot);
  }
}

__global__ void zero_out_kernel(float* __restrict__ out, int out_size) {
  int i = blockIdx.x * blockDim.x + threadIdx.x;
  if (i < out_size) out[i] = 0.f;
}

extern "C" void kernel_launch(void* const* d_in, const int* in_sizes, int n_in,
                              void* d_out, int out_size, void* d_ws, size_t ws_size,
                              hipStream_t stream) {
  const float* x0 = (const float*)d_in[0];
  const float* v = (const float*)d_in[1];
  const float* beta = (const float*)d_in[2];
  const float* times = (const float*)d_in[3];
  const int* pairs = (const int*)d_in[4];
  const int* nodes = (const int*)d_in[5];
  int N = in_sizes[2];          // 8192
  int E = in_sizes[3];          // 100000
  int S = in_sizes[5];          // 256
  float* out = (float*)d_out;
  const int ND = N * DD;

  // workspace layout (256B-aligned chunks)
  size_t off = 0;
  auto alloc = [&](size_t bytes) { size_t o = off; off = (off + bytes + 255) & ~(size_t)255; return o; };
  size_t oPh = alloc((size_t)BINSN * ND * sizeof(__half));
  size_t oPs = alloc((size_t)BINSN * S * DD * sizeof(float));
  size_t oVs = alloc((size_t)BINSN * S * DD * sizeof(float));
  size_t oBs = alloc((size_t)S * sizeof(float));
  size_t oSl = alloc((size_t)NSLOT * SLOT_STRIDE * sizeof(float));
  bool useFast = (ws_size >= off);

  if (useFast) {
    char* base = (char*)d_ws;
    __half* Ph = (__half*)(base + oPh);
    float* Ps = (float*)(base + oPs);
    float* Vs = (float*)(base + oVs);
    float* Bs = (float*)(base + oBs);
    float* slots = (float*)(base + oSl);

    int ND2 = ND / 2;
    int posBlocks = (ND2 + 255) / 256;                       // 512
    int subBlocks = (S * DD + 255) / 256;                    // 32
    prep_kernel<<<posBlocks + subBlocks, 256, 0, stream>>>(
        (const float2*)x0, (const float2*)v, (__half2*)Ph, ND2,
        x0, v, beta, nodes, Ps, Vs, Bs, N, S, posBlocks, slots);

    int evBlocks = (E * 32 + 255) / 256;                     // 12500
    event_kernel_h<<<evBlocks, 256, 0, stream>>>(Ph, v, beta, times, pairs,
                                                 N, E, slots);

    int ntr = (S + TS2 - 1) / TS2;                           // 8
    int nTiles = ntr * (ntr + 1) / 2;                        // 36
    integral_v8<<<nTiles * BINSN, 256, 0, stream>>>(
        (const float4*)Ps, (const float4*)Vs, Bs, S, ntr, nTiles, slots);

    finalize_kernel<<<1, 256, 0, stream>>>(slots, out, out_size);
  } else {
    zero_out_kernel<<<(out_size + 255) / 256, 256, 0, stream>>>(out, out_size);
    event_kernel_fb<<<2048, 256, 0, stream>>>(out == nullptr ? x0 : x0, v, beta, times, pairs, N, E, out);
    int npair = S * (S - 1) / 2;
    int nPairChunks = (npair + 255) / 256;
    integral_fb<<<nPairChunks, 256, 0, stream>>>(
        (const float4*)x0, (const float4*)v, beta, nodes, N, S, npair,
        nPairChunks, out);
  }
}

// Round 10
// 53.231 us; speedup vs baseline: 3.5896x; 3.5896x over previous
//
#include <hip/hip_runtime.h>
#include <hip/hip_fp16.h>
#include <math.h>

#define BINSN 50
#define DD 32
#define DD4 8
#define BWF 0.02f            // fp32 of LAST_TIME/BINS
#define EPSF 1e-6f
#define SQRTPI_HALF 0.8862269254527580f
#define TS2 32               // node tile size for integral path
#define NSLOT 256
#define SLOT_STRIDE 16       // floats; 64B apart -> no contention

// Branch-free erf, Abramowitz-Stegun 7.1.26, |err| <= 1.5e-7 absolute.
__device__ __forceinline__ float fast_erff(float x) {
  float ax = fabsf(x);
  float t = __fdividef(1.0f, fmaf(0.3275911f, ax, 1.0f));
  float p = t * fmaf(t, fmaf(t, fmaf(t, fmaf(t, 1.061405429f, -1.453152027f),
                                     1.421413741f), -0.284496736f), 0.254829592f);
  float y = 1.0f - p * __expf(-ax * ax);
  return copysignf(y, x);
}

__device__ __forceinline__ void block_reduce_to_slot(float acc, float* slots) {
#pragma unroll
  for (int m = 32; m >= 1; m >>= 1) acc += __shfl_xor(acc, m, 64);
  __shared__ float red[4];
  int wid = threadIdx.x >> 6;
  if ((threadIdx.x & 63) == 0) red[wid] = acc;
  __syncthreads();
  if (threadIdx.x == 0) {
    float tot = red[0] + red[1] + red[2] + red[3];
    atomicAdd(&slots[(blockIdx.x & (NSLOT - 1)) * SLOT_STRIDE], tot);
  }
}

// ---------------- Kernel 1: fused {pos->fp16 Ph} + {subset Ps/Vs/Bs} -----------
// blocks [0, posBlocks): Ph[b,n,d] = half(x0 + BW*cumsum(v)), ONE dim/thread
// (16 waves/CU for latency hiding of the 79MB stream).
// blocks [posBlocks, ...): one thread per (s,d), serial over bins, f32.
__global__ __launch_bounds__(256)
void prep_kernel(const float* __restrict__ x0, const float* __restrict__ v,
                 __half* __restrict__ Ph,
                 const float* __restrict__ beta, const int* __restrict__ nodes,
                 float* __restrict__ Ps, float* __restrict__ Vs,
                 float* __restrict__ Bs,
                 int N, int S, int posBlocks,
                 float* __restrict__ slots) {
  int tx = threadIdx.x;
  const int ND = N * DD;
  if (blockIdx.x == 0) {
    for (int o = tx; o < NSLOT * SLOT_STRIDE; o += blockDim.x) slots[o] = 0.f;
  }
  if ((int)blockIdx.x < posBlocks) {
    int idx = blockIdx.x * blockDim.x + tx;
    if (idx >= ND) return;
    float run = x0[idx];
#pragma unroll 10
    for (int b = 0; b < BINSN; ++b) {
      size_t off = (size_t)b * ND + idx;
      Ph[off] = __float2half(run);
      run = fmaf(BWF, v[off], run);
    }
  } else {
    int flat = (blockIdx.x - posBlocks) * blockDim.x + tx;  // (s,d)
    if (flat >= S * DD) return;
    int d = flat & (DD - 1);
    int s = flat >> 5;
    int node = nodes[s];
    size_t base = (size_t)node * DD + d;
    float run = x0[base];
    if (d == 0) Bs[s] = beta[node];
#pragma unroll 10
    for (int b = 0; b < BINSN; ++b) {
      size_t so = ((size_t)b * S + s) * DD + d;
      float vv = v[(size_t)b * ND + base];
      Ps[so] = run;
      Vs[so] = vv;
      run = fmaf(BWF, vv, run);
    }
  }
}

// ---------------- Kernel 2: -sum(log_intensity), TWO events per 32-lane slot ---
// Two independent gather chains in flight per slot (MLP); half the blocks.
__global__ __launch_bounds__(256)
void event_kernel_h(const __half* __restrict__ Ph,
                    const float* __restrict__ v,
                    const float* __restrict__ beta,
                    const float* __restrict__ times,
                    const int* __restrict__ pairs,
                    int N, int E, int nHalf, float* __restrict__ slots) {
  const int ND = N * DD;
  const int lane = threadIdx.x & 31;
  int slotId = (int)((blockIdx.x * blockDim.x + threadIdx.x) >> 5);
  float acc = 0.f;

#define EV_BODY(EIDX)                                                          \
  {                                                                            \
    float t = times[EIDX];                                                     \
    int p0 = pairs[EIDX];                                                      \
    int p1 = pairs[E + (EIDX)];                                                \
    float fb = floorf(t / BWF);                                                \
    float res = fmaf(-BWF, fb, t);                                             \
    int b = (int)fb;                                                           \
    b = b < 0 ? 0 : (b > BINSN - 1 ? BINSN - 1 : b);                           \
    size_t o0 = (size_t)p0 * DD + lane;                                        \
    size_t o1 = (size_t)p1 * DD + lane;                                        \
    size_t bo = (size_t)b * ND;                                                \
    float dP = __half2float(Ph[bo + o0]) - __half2float(Ph[bo + o1]);          \
    float dx = dP + res * (v[bo + o0] - v[bo + o1]);                           \
    float s = dx * dx;                                                         \
    _Pragma("unroll")                                                          \
    for (int m = 16; m >= 1; m >>= 1) s += __shfl_xor(s, m, 64);               \
    if (lane == 0) acc += s - beta[p0] - beta[p1];                             \
  }

  int e0 = slotId;
  int e1 = slotId + nHalf;
  if (e0 < E) EV_BODY(e0);
  if (e1 < E) EV_BODY(e1);
#undef EV_BODY

  block_reduce_to_slot(acc, slots);
}

// ---------------- Kernel 3: survival integral, one (32x32 tile, bin) per block --
// Dense L2/L3-resident Ps/Vs/Bs; one sync; fully scalarized; slot sink only.
// NO occupancy cap (round-9 lesson: forcing VGPR below ~150 live regs spills).
// unroll 4 on q-loop: shorter live ranges, hoping for natural VGPR <= 128.
__global__ __launch_bounds__(256)
void integral_v9(const float4* __restrict__ Ps4,
                 const float4* __restrict__ Vs4,
                 const float* __restrict__ Bs,
                 int S, int nTileRows, int nTiles,
                 float* __restrict__ slots) {
  int tile = blockIdx.x % nTiles;
  int b = blockIdx.x / nTiles;
  int ti = 0;
  {
    int rem = tile;
    while (rem >= nTileRows - ti) { rem -= (nTileRows - ti); ++ti; }
    tile = rem;
  }
  int tj = ti + tile;

  __shared__ float sP[64][36];   // pad 36: strided j-reads -> free 2-way conflict
  __shared__ float sV[64][36];
  __shared__ float sB[64];

  int tx = threadIdx.x;
  {
    int row = tx >> 3, q = tx & 7;
    int g0 = ti * TS2 + row;
    if (g0 >= S) g0 = S - 1;
    size_t a0 = ((size_t)b * S + g0) * DD4 + q;
    *(float4*)&sP[row][q * 4] = Ps4[a0];
    *(float4*)&sV[row][q * 4] = Vs4[a0];
    int g1 = tj * TS2 + row;
    if (g1 >= S) g1 = S - 1;
    size_t a1 = ((size_t)b * S + g1) * DD4 + q;
    *(float4*)&sP[row + 32][q * 4] = Ps4[a1];
    *(float4*)&sV[row + 32][q * 4] = Vs4[a1];
    if (q == 0) { sB[row] = Bs[g0]; sB[row + 32] = Bs[g1]; }
  }
  __syncthreads();

  int ii = tx >> 4;
  int jj = tx & 15;

  float sdd00 = 0.f, sxd00 = 0.f, sxx00 = 0.f;
  float sdd01 = 0.f, sxd01 = 0.f, sxx01 = 0.f;
  float sdd10 = 0.f, sxd10 = 0.f, sxx10 = 0.f;
  float sdd11 = 0.f, sxd11 = 0.f, sxx11 = 0.f;

#define CELL(SDD, SXD, SXX, PA, PB, VA, VB)                                    \
  {                                                                            \
    float dx0 = PA.x - PB.x, dx1 = PA.y - PB.y;                                \
    float dx2 = PA.z - PB.z, dx3 = PA.w - PB.w;                                \
    float dv0 = VA.x - VB.x, dv1 = VA.y - VB.y;                                \
    float dv2 = VA.z - VB.z, dv3 = VA.w - VB.w;                                \
    SDD = fmaf(dv0, dv0, fmaf(dv1, dv1, fmaf(dv2, dv2, fmaf(dv3, dv3, SDD)))); \
    SXD = fmaf(dx0, dv0, fmaf(dx1, dv1, fmaf(dx2, dv2, fmaf(dx3, dv3, SXD)))); \
    SXX = fmaf(dx0, dx0, fmaf(dx1, dx1, fmaf(dx2, dx2, fmaf(dx3, dx3, SXX)))); \
  }

#pragma unroll 4
  for (int q = 0; q < 8; ++q) {
    const float4 Pi0 = *(const float4*)&sP[ii][q * 4];
    const float4 Pi1 = *(const float4*)&sP[ii + 16][q * 4];
    const float4 Pj0 = *(const float4*)&sP[TS2 + jj][q * 4];
    const float4 Pj1 = *(const float4*)&sP[TS2 + jj + 16][q * 4];
    const float4 Vi0 = *(const float4*)&sV[ii][q * 4];
    const float4 Vi1 = *(const float4*)&sV[ii + 16][q * 4];
    const float4 Vj0 = *(const float4*)&sV[TS2 + jj][q * 4];
    const float4 Vj1 = *(const float4*)&sV[TS2 + jj + 16][q * 4];
    CELL(sdd00, sxd00, sxx00, Pi0, Pj0, Vi0, Vj0);
    CELL(sdd01, sxd01, sxx01, Pi0, Pj1, Vi0, Vj1);
    CELL(sdd10, sxd10, sxx10, Pi1, Pj0, Vi1, Vj0);
    CELL(sdd11, sxd11, sxx11, Pi1, Pj1, Vi1, Vj1);
  }
#undef CELL

  float acc = 0.f;
  const float tlo = (float)b * BWF;
  const float thi = (float)(b + 1) * BWF;

#define FIN(SDD, SXD, SXX, AOFF, COFF)                                         \
  {                                                                            \
    int li = ii + (AOFF), lj = jj + (COFF);                                    \
    int gi = ti * TS2 + li, gj = tj * TS2 + lj;                                \
    if (gi < gj && gj < S) {                                                   \
      float ndv = sqrtf(SDD);                                                  \
      float inv = __fdividef(1.0f, ndv + EPSF);                                \
      float r = SXD * inv;                                                     \
      float bij = sB[li] + sB[TS2 + lj];                                       \
      float t1 = __expf(bij + fmaf(r, r, -(SXX)));                             \
      float lo = fmaf(tlo, ndv, r);                                            \
      float hi = fmaf(thi, ndv, r);                                            \
      acc += SQRTPI_HALF * inv * t1 * (fast_erff(hi) - fast_erff(lo));         \
    }                                                                          \
  }

  FIN(sdd00, sxd00, sxx00, 0, 0);
  FIN(sdd01, sxd01, sxx01, 0, 16);
  FIN(sdd10, sxd10, sxx10, 16, 0);
  FIN(sdd11, sxd11, sxx11, 16, 16);
#undef FIN

  block_reduce_to_slot(acc, slots);
}

// ---------------- finalize: sum slots -> out[0] ----------------
__global__ void finalize_kernel(const float* __restrict__ slots,
                                float* __restrict__ out, int out_size) {
  float a = slots[threadIdx.x * SLOT_STRIDE];
#pragma unroll
  for (int m = 32; m >= 1; m >>= 1) a += __shfl_xor(a, m, 64);
  __shared__ float red[4];
  int wid = threadIdx.x >> 6;
  if ((threadIdx.x & 63) == 0) red[wid] = a;
  __syncthreads();
  if (threadIdx.x == 0) out[0] = red[0] + red[1] + red[2] + red[3];
  if (threadIdx.x > 0 && threadIdx.x < out_size) out[threadIdx.x] = 0.f;
}

// ---------------- Fallback kernels (workspace too small) ----------------
__global__ void event_kernel_fb(const float* __restrict__ x0,
                                const float* __restrict__ v,
                                const float* __restrict__ beta,
                                const float* __restrict__ times,
                                const int* __restrict__ pairs,
                                int N, int E, float* __restrict__ out) {
  const int ND = N * DD;
  const int lane = threadIdx.x & 31;
  int slot = (blockIdx.x * blockDim.x + threadIdx.x) >> 5;
  const int nslots = (gridDim.x * blockDim.x) >> 5;
  float acc = 0.f;
  for (int e = slot; e < E; e += nslots) {
    float t = times[e];
    int p0 = pairs[e];
    int p1 = pairs[E + e];
    float fb = floorf(t / BWF);
    float res = fmaf(-BWF, fb, t);
    int b = (int)fb;
    b = b < 0 ? 0 : (b > BINSN - 1 ? BINSN - 1 : b);
    size_t o0 = (size_t)p0 * DD + lane;
    size_t o1 = (size_t)p1 * DD + lane;
    size_t bo = (size_t)b * ND;
    float c0 = 0.f, c1 = 0.f;
    for (int k = 0; k < b; ++k) {
      size_t ko = (size_t)k * ND;
      c0 += v[ko + o0];
      c1 += v[ko + o1];
    }
    float dx = (x0[o0] - x0[o1]) + BWF * (c0 - c1) + res * (v[bo + o0] - v[bo + o1]);
    float s = dx * dx;
#pragma unroll
    for (int m = 16; m >= 1; m >>= 1) s += __shfl_xor(s, m, 64);
    if (lane == 0) acc += s - beta[p0] - beta[p1];
  }
#pragma unroll
  for (int m = 32; m >= 1; m >>= 1) acc += __shfl_xor(acc, m, 64);
  __shared__ float smem[16];
  int wid = threadIdx.x >> 6;
  if ((threadIdx.x & 63) == 0) smem[wid] = acc;
  __syncthreads();
  if (threadIdx.x == 0) {
    float tot = 0.f;
    int nw = blockDim.x >> 6;
    for (int w = 0; w < nw; ++w) tot += smem[w];
    atomicAdd(out, tot);
  }
}

__global__ void integral_fb(const float4* __restrict__ x04,
                            const float4* __restrict__ v4,
                            const float* __restrict__ beta,
                            const int* __restrict__ nodes,
                            int N, int S, int npair, int nPairChunks,
                            float* __restrict__ out) {
  const int nd4 = N * DD4;
  int p = (blockIdx.x % nPairChunks) * blockDim.x + threadIdx.x;
  float acc = 0.f;
  if (p < npair) {
    const int twoSm1 = 2 * S - 1;
    int i = (int)((twoSm1 - sqrt((double)twoSm1 * twoSm1 - 8.0 * (double)p)) * 0.5);
    if (i < 0) i = 0;
    if (i > S - 2) i = S - 2;
#define BASE(ii) ((ii) * (twoSm1 - (ii)) / 2)
    while (i < S - 2 && BASE(i + 1) <= p) ++i;
    while (i > 0 && BASE(i) > p) --i;
    int j = i + 1 + (p - BASE(i));
#undef BASE
    int u0 = nodes[i], u1 = nodes[j];
    float bij = beta[u0] + beta[u1];
    size_t r0 = (size_t)u0 * DD4;
    size_t r1 = (size_t)u1 * DD4;
    float dxt[DD];
#pragma unroll
    for (int q = 0; q < DD4; ++q) {
      float4 a = x04[r0 + q];
      float4 bb = x04[r1 + q];
      dxt[q * 4 + 0] = a.x - bb.x;
      dxt[q * 4 + 1] = a.y - bb.y;
      dxt[q * 4 + 2] = a.z - bb.z;
      dxt[q * 4 + 3] = a.w - bb.w;
    }
    for (int b = 0; b < BINSN; ++b) {
      size_t bo4 = (size_t)b * nd4;
      float sdd = 0.f, sxd = 0.f, sxx = 0.f;
#pragma unroll
      for (int q = 0; q < DD4; ++q) {
        float4 a = v4[bo4 + r0 + q];
        float4 c = v4[bo4 + r1 + q];
        float d0 = a.x - c.x, d1 = a.y - c.y, d2 = a.z - c.z, d3 = a.w - c.w;
        float y0 = dxt[q * 4 + 0], y1 = dxt[q * 4 + 1];
        float y2 = dxt[q * 4 + 2], y3 = dxt[q * 4 + 3];
        sdd += d0 * d0 + d1 * d1 + d2 * d2 + d3 * d3;
        sxd += y0 * d0 + y1 * d1 + y2 * d2 + y3 * d3;
        sxx += y0 * y0 + y1 * y1 + y2 * y2 + y3 * y3;
        dxt[q * 4 + 0] = fmaf(BWF, d0, y0);
        dxt[q * 4 + 1] = fmaf(BWF, d1, y1);
        dxt[q * 4 + 2] = fmaf(BWF, d2, y2);
        dxt[q * 4 + 3] = fmaf(BWF, d3, y3);
      }
      float ndv = sqrtf(sdd);
      float inv = __fdividef(1.0f, ndv + EPSF);
      float r = sxd * inv;
      float t1 = __expf(bij + r * r - sxx);
      float lo = fmaf((float)b * BWF, ndv, r);
      float hi = fmaf((float)(b + 1) * BWF, ndv, r);
      acc += SQRTPI_HALF * inv * t1 * (fast_erff(hi) - fast_erff(lo));
    }
  }
#pragma unroll
  for (int m = 32; m >= 1; m >>= 1) acc += __shfl_xor(acc, m, 64);
  __shared__ float smem[16];
  int wid = threadIdx.x >> 6;
  if ((threadIdx.x & 63) == 0) smem[wid] = acc;
  __syncthreads();
  if (threadIdx.x == 0) {
    float tot = 0.f;
    int nw = blockDim.x >> 6;
    for (int w = 0; w < nw; ++w) tot += smem[w];
    atomicAdd(out, tot);
  }
}

__global__ void zero_out_kernel(float* __restrict__ out, int out_size) {
  int i = blockIdx.x * blockDim.x + threadIdx.x;
  if (i < out_size) out[i] = 0.f;
}

extern "C" void kernel_launch(void* const* d_in, const int* in_sizes, int n_in,
                              void* d_out, int out_size, void* d_ws, size_t ws_size,
                              hipStream_t stream) {
  const float* x0 = (const float*)d_in[0];
  const float* v = (const float*)d_in[1];
  const float* beta = (const float*)d_in[2];
  const float* times = (const float*)d_in[3];
  const int* pairs = (const int*)d_in[4];
  const int* nodes = (const int*)d_in[5];
  int N = in_sizes[2];          // 8192
  int E = in_sizes[3];          // 100000
  int S = in_sizes[5];          // 256
  float* out = (float*)d_out;
  const int ND = N * DD;

  // workspace layout (256B-aligned chunks)
  size_t off = 0;
  auto alloc = [&](size_t bytes) { size_t o = off; off = (off + bytes + 255) & ~(size_t)255; return o; };
  size_t oPh = alloc((size_t)BINSN * ND * sizeof(__half));
  size_t oPs = alloc((size_t)BINSN * S * DD * sizeof(float));
  size_t oVs = alloc((size_t)BINSN * S * DD * sizeof(float));
  size_t oBs = alloc((size_t)S * sizeof(float));
  size_t oSl = alloc((size_t)NSLOT * SLOT_STRIDE * sizeof(float));
  bool useFast = (ws_size >= off);

  if (useFast) {
    char* base = (char*)d_ws;
    __half* Ph = (__half*)(base + oPh);
    float* Ps = (float*)(base + oPs);
    float* Vs = (float*)(base + oVs);
    float* Bs = (float*)(base + oBs);
    float* slots = (float*)(base + oSl);

    int posBlocks = (ND + 255) / 256;                        // 1024
    int subBlocks = (S * DD + 255) / 256;                    // 32
    prep_kernel<<<posBlocks + subBlocks, 256, 0, stream>>>(
        x0, v, Ph, beta, nodes, Ps, Vs, Bs, N, S, posBlocks, slots);

    int nHalf = (E + 1) / 2;                                 // 50000
    int evBlocks = (nHalf * 32 + 255) / 256;                 // 6250
    event_kernel_h<<<evBlocks, 256, 0, stream>>>(Ph, v, beta, times, pairs,
                                                 N, E, nHalf, slots);

    int ntr = (S + TS2 - 1) / TS2;                           // 8
    int nTiles = ntr * (ntr + 1) / 2;                        // 36
    integral_v9<<<nTiles * BINSN, 256, 0, stream>>>(
        (const float4*)Ps, (const float4*)Vs, Bs, S, ntr, nTiles, slots);

    finalize_kernel<<<1, 256, 0, stream>>>(slots, out, out_size);
  } else {
    zero_out_kernel<<<(out_size + 255) / 256, 256, 0, stream>>>(out, out_size);
    event_kernel_fb<<<2048, 256, 0, stream>>>(x0, v, beta, times, pairs, N, E, out);
    int npair = S * (S - 1) / 2;
    int nPairChunks = (npair + 255) / 256;
    integral_fb<<<nPairChunks, 256, 0, stream>>>(
        (const float4*)x0, (const float4*)v, beta, nodes, N, S, npair,
        nPairChunks, out);
  }
}

// Round 11
// 51.378 us; speedup vs baseline: 3.7190x; 1.0361x over previous
//
#include <hip/hip_runtime.h>
#include <hip/hip_fp16.h>
#include <math.h>

#define BINSN 50
#define DD 32
#define DD4 8
#define BWF 0.02f            // fp32 of LAST_TIME/BINS
#define EPSF 1e-6f
#define SQRTPI_HALF 0.8862269254527580f
#define TS2 32               // node tile size for integral path
#define NSLOT 256
#define SLOT_STRIDE 16       // floats; 64B apart -> no contention
#define SKIP_ARG -25.0f      // exp(arg) < 1.4e-11: cell contribution < 2.5e-5

// Branch-free erf, Abramowitz-Stegun 7.1.26, |err| <= 1.5e-7 absolute.
__device__ __forceinline__ float fast_erff(float x) {
  float ax = fabsf(x);
  float t = __fdividef(1.0f, fmaf(0.3275911f, ax, 1.0f));
  float p = t * fmaf(t, fmaf(t, fmaf(t, fmaf(t, 1.061405429f, -1.453152027f),
                                     1.421413741f), -0.284496736f), 0.254829592f);
  float y = 1.0f - p * __expf(-ax * ax);
  return copysignf(y, x);
}

__device__ __forceinline__ void block_reduce_to_slot(float acc, float* slots) {
#pragma unroll
  for (int m = 32; m >= 1; m >>= 1) acc += __shfl_xor(acc, m, 64);
  __shared__ float red[4];
  int wid = threadIdx.x >> 6;
  if ((threadIdx.x & 63) == 0) red[wid] = acc;
  __syncthreads();
  if (threadIdx.x == 0) {
    float tot = red[0] + red[1] + red[2] + red[3];
    atomicAdd(&slots[(blockIdx.x & (NSLOT - 1)) * SLOT_STRIDE], tot);
  }
}

// ---------------- Kernel 1: fused {pos->fp16 Ph} + {subset Ps/Vs/Bs} -----------
__global__ __launch_bounds__(256)
void prep_kernel(const float* __restrict__ x0, const float* __restrict__ v,
                 __half* __restrict__ Ph,
                 const float* __restrict__ beta, const int* __restrict__ nodes,
                 float* __restrict__ Ps, float* __restrict__ Vs,
                 float* __restrict__ Bs,
                 int N, int S, int posBlocks,
                 float* __restrict__ slots) {
  int tx = threadIdx.x;
  const int ND = N * DD;
  if (blockIdx.x == 0) {
    for (int o = tx; o < NSLOT * SLOT_STRIDE; o += blockDim.x) slots[o] = 0.f;
  }
  if ((int)blockIdx.x < posBlocks) {
    int idx = blockIdx.x * blockDim.x + tx;
    if (idx >= ND) return;
    float run = x0[idx];
#pragma unroll 10
    for (int b = 0; b < BINSN; ++b) {
      size_t off = (size_t)b * ND + idx;
      Ph[off] = __float2half(run);
      run = fmaf(BWF, v[off], run);
    }
  } else {
    int flat = (blockIdx.x - posBlocks) * blockDim.x + tx;  // (s,d)
    if (flat >= S * DD) return;
    int d = flat & (DD - 1);
    int s = flat >> 5;
    int node = nodes[s];
    size_t base = (size_t)node * DD + d;
    float run = x0[base];
    if (d == 0) Bs[s] = beta[node];
#pragma unroll 10
    for (int b = 0; b < BINSN; ++b) {
      size_t so = ((size_t)b * S + s) * DD + d;
      float vv = v[(size_t)b * ND + base];
      Ps[so] = run;
      Vs[so] = vv;
      run = fmaf(BWF, vv, run);
    }
  }
}

// ---------------- Kernel 2: -sum(log_intensity), FOUR events per 32-lane slot --
// Four independent gather chains in flight per slot (MLP); quarter the blocks.
__global__ __launch_bounds__(256)
void event_kernel_h(const __half* __restrict__ Ph,
                    const float* __restrict__ v,
                    const float* __restrict__ beta,
                    const float* __restrict__ times,
                    const int* __restrict__ pairs,
                    int N, int E, int nQ, float* __restrict__ slots) {
  const int ND = N * DD;
  const int lane = threadIdx.x & 31;
  int slotId = (int)((blockIdx.x * blockDim.x + threadIdx.x) >> 5);
  float acc = 0.f;

#define EV_BODY(EIDX)                                                          \
  {                                                                            \
    float t = times[EIDX];                                                     \
    int p0 = pairs[EIDX];                                                      \
    int p1 = pairs[E + (EIDX)];                                                \
    float fb = floorf(t / BWF);                                                \
    float res = fmaf(-BWF, fb, t);                                             \
    int b = (int)fb;                                                           \
    b = b < 0 ? 0 : (b > BINSN - 1 ? BINSN - 1 : b);                           \
    size_t o0 = (size_t)p0 * DD + lane;                                        \
    size_t o1 = (size_t)p1 * DD + lane;                                        \
    size_t bo = (size_t)b * ND;                                                \
    float dP = __half2float(Ph[bo + o0]) - __half2float(Ph[bo + o1]);          \
    float dx = dP + res * (v[bo + o0] - v[bo + o1]);                           \
    float s = dx * dx;                                                         \
    _Pragma("unroll")                                                          \
    for (int m = 16; m >= 1; m >>= 1) s += __shfl_xor(s, m, 64);               \
    if (lane == 0) acc += s - beta[p0] - beta[p1];                             \
  }

  int e0 = slotId;
  int e1 = slotId + nQ;
  int e2 = slotId + 2 * nQ;
  int e3 = slotId + 3 * nQ;
  if (e0 < E) EV_BODY(e0);
  if (e1 < E) EV_BODY(e1);
  if (e2 < E) EV_BODY(e2);
  if (e3 < E) EV_BODY(e3);
#undef EV_BODY

  block_reduce_to_slot(acc, slots);
}

// ---------------- Kernel 3: survival integral, one (32x32 tile, bin) per block --
// Dense L2-resident Ps/Vs/Bs; one sync; fully scalarized; slot sink only.
// Epilogue trans ops (sqrt/rcp/exp/erf) predicated on arg > SKIP_ARG: for
// random embeddings most cells have exp(bij+r^2-sxx) ~ e^-60 -> skip is free
// accuracy-wise (bound: 2.5e-5/cell * 1.6M cells << 1.3e5 threshold).
__global__ __launch_bounds__(256)
void integral_v10(const float4* __restrict__ Ps4,
                  const float4* __restrict__ Vs4,
                  const float* __restrict__ Bs,
                  int S, int nTileRows, int nTiles,
                  float* __restrict__ slots) {
  int tile = blockIdx.x % nTiles;
  int b = blockIdx.x / nTiles;
  int ti = 0;
  {
    int rem = tile;
    while (rem >= nTileRows - ti) { rem -= (nTileRows - ti); ++ti; }
    tile = rem;
  }
  int tj = ti + tile;

  __shared__ float sP[64][36];   // pad 36: strided j-reads -> free 2-way conflict
  __shared__ float sV[64][36];
  __shared__ float sB[64];

  int tx = threadIdx.x;
  {
    int row = tx >> 3, q = tx & 7;
    int g0 = ti * TS2 + row;
    if (g0 >= S) g0 = S - 1;
    size_t a0 = ((size_t)b * S + g0) * DD4 + q;
    *(float4*)&sP[row][q * 4] = Ps4[a0];
    *(float4*)&sV[row][q * 4] = Vs4[a0];
    int g1 = tj * TS2 + row;
    if (g1 >= S) g1 = S - 1;
    size_t a1 = ((size_t)b * S + g1) * DD4 + q;
    *(float4*)&sP[row + 32][q * 4] = Ps4[a1];
    *(float4*)&sV[row + 32][q * 4] = Vs4[a1];
    if (q == 0) { sB[row] = Bs[g0]; sB[row + 32] = Bs[g1]; }
  }
  __syncthreads();

  int ii = tx >> 4;
  int jj = tx & 15;

  float sdd00 = 0.f, sxd00 = 0.f, sxx00 = 0.f;
  float sdd01 = 0.f, sxd01 = 0.f, sxx01 = 0.f;
  float sdd10 = 0.f, sxd10 = 0.f, sxx10 = 0.f;
  float sdd11 = 0.f, sxd11 = 0.f, sxx11 = 0.f;

#define CELL(SDD, SXD, SXX, PA, PB, VA, VB)                                    \
  {                                                                            \
    float dx0 = PA.x - PB.x, dx1 = PA.y - PB.y;                                \
    float dx2 = PA.z - PB.z, dx3 = PA.w - PB.w;                                \
    float dv0 = VA.x - VB.x, dv1 = VA.y - VB.y;                                \
    float dv2 = VA.z - VB.z, dv3 = VA.w - VB.w;                                \
    SDD = fmaf(dv0, dv0, fmaf(dv1, dv1, fmaf(dv2, dv2, fmaf(dv3, dv3, SDD)))); \
    SXD = fmaf(dx0, dv0, fmaf(dx1, dv1, fmaf(dx2, dv2, fmaf(dx3, dv3, SXD)))); \
    SXX = fmaf(dx0, dx0, fmaf(dx1, dx1, fmaf(dx2, dx2, fmaf(dx3, dx3, SXX)))); \
  }

#pragma unroll 4
  for (int q = 0; q < 8; ++q) {
    const float4 Pi0 = *(const float4*)&sP[ii][q * 4];
    const float4 Pi1 = *(const float4*)&sP[ii + 16][q * 4];
    const float4 Pj0 = *(const float4*)&sP[TS2 + jj][q * 4];
    const float4 Pj1 = *(const float4*)&sP[TS2 + jj + 16][q * 4];
    const float4 Vi0 = *(const float4*)&sV[ii][q * 4];
    const float4 Vi1 = *(const float4*)&sV[ii + 16][q * 4];
    const float4 Vj0 = *(const float4*)&sV[TS2 + jj][q * 4];
    const float4 Vj1 = *(const float4*)&sV[TS2 + jj + 16][q * 4];
    CELL(sdd00, sxd00, sxx00, Pi0, Pj0, Vi0, Vj0);
    CELL(sdd01, sxd01, sxx01, Pi0, Pj1, Vi0, Vj1);
    CELL(sdd10, sxd10, sxx10, Pi1, Pj0, Vi1, Vj0);
    CELL(sdd11, sxd11, sxx11, Pi1, Pj1, Vi1, Vj1);
  }
#undef CELL

  float acc = 0.f;
  const float tlo = (float)b * BWF;
  const float thi = (float)(b + 1) * BWF;

#define FIN(SDD, SXD, SXX, AOFF, COFF)                                         \
  {                                                                            \
    int li = ii + (AOFF), lj = jj + (COFF);                                    \
    int gi = ti * TS2 + li, gj = tj * TS2 + lj;                                \
    if (gi < gj && gj < S) {                                                   \
      float ndv = sqrtf(SDD);                                                  \
      float inv = __fdividef(1.0f, ndv + EPSF);                                \
      float r = SXD * inv;                                                     \
      float bij = sB[li] + sB[TS2 + lj];                                       \
      float arg = bij + fmaf(r, r, -(SXX));                                    \
      if (arg > SKIP_ARG) {                                                    \
        float t1 = __expf(arg);                                                \
        float lo = fmaf(tlo, ndv, r);                                          \
        float hi = fmaf(thi, ndv, r);                                          \
        acc += SQRTPI_HALF * inv * t1 * (fast_erff(hi) - fast_erff(lo));       \
      }                                                                        \
    }                                                                          \
  }

  FIN(sdd00, sxd00, sxx00, 0, 0);
  FIN(sdd01, sxd01, sxx01, 0, 16);
  FIN(sdd10, sxd10, sxx10, 16, 0);
  FIN(sdd11, sxd11, sxx11, 16, 16);
#undef FIN

  block_reduce_to_slot(acc, slots);
}

// ---------------- finalize: sum slots -> out[0] ----------------
__global__ void finalize_kernel(const float* __restrict__ slots,
                                float* __restrict__ out, int out_size) {
  float a = slots[threadIdx.x * SLOT_STRIDE];
#pragma unroll
  for (int m = 32; m >= 1; m >>= 1) a += __shfl_xor(a, m, 64);
  __shared__ float red[4];
  int wid = threadIdx.x >> 6;
  if ((threadIdx.x & 63) == 0) red[wid] = a;
  __syncthreads();
  if (threadIdx.x == 0) out[0] = red[0] + red[1] + red[2] + red[3];
  if (threadIdx.x > 0 && threadIdx.x < out_size) out[threadIdx.x] = 0.f;
}

// ---------------- Fallback kernels (workspace too small) ----------------
__global__ void event_kernel_fb(const float* __restrict__ x0,
                                const float* __restrict__ v,
                                const float* __restrict__ beta,
                                const float* __restrict__ times,
                                const int* __restrict__ pairs,
                                int N, int E, float* __restrict__ out) {
  const int ND = N * DD;
  const int lane = threadIdx.x & 31;
  int slot = (blockIdx.x * blockDim.x + threadIdx.x) >> 5;
  const int nslots = (gridDim.x * blockDim.x) >> 5;
  float acc = 0.f;
  for (int e = slot; e < E; e += nslots) {
    float t = times[e];
    int p0 = pairs[e];
    int p1 = pairs[E + e];
    float fb = floorf(t / BWF);
    float res = fmaf(-BWF, fb, t);
    int b = (int)fb;
    b = b < 0 ? 0 : (b > BINSN - 1 ? BINSN - 1 : b);
    size_t o0 = (size_t)p0 * DD + lane;
    size_t o1 = (size_t)p1 * DD + lane;
    size_t bo = (size_t)b * ND;
    float c0 = 0.f, c1 = 0.f;
    for (int k = 0; k < b; ++k) {
      size_t ko = (size_t)k * ND;
      c0 += v[ko + o0];
      c1 += v[ko + o1];
    }
    float dx = (x0[o0] - x0[o1]) + BWF * (c0 - c1) + res * (v[bo + o0] - v[bo + o1]);
    float s = dx * dx;
#pragma unroll
    for (int m = 16; m >= 1; m >>= 1) s += __shfl_xor(s, m, 64);
    if (lane == 0) acc += s - beta[p0] - beta[p1];
  }
#pragma unroll
  for (int m = 32; m >= 1; m >>= 1) acc += __shfl_xor(acc, m, 64);
  __shared__ float smem[16];
  int wid = threadIdx.x >> 6;
  if ((threadIdx.x & 63) == 0) smem[wid] = acc;
  __syncthreads();
  if (threadIdx.x == 0) {
    float tot = 0.f;
    int nw = blockDim.x >> 6;
    for (int w = 0; w < nw; ++w) tot += smem[w];
    atomicAdd(out, tot);
  }
}

__global__ void integral_fb(const float4* __restrict__ x04,
                            const float4* __restrict__ v4,
                            const float* __restrict__ beta,
                            const int* __restrict__ nodes,
                            int N, int S, int npair, int nPairChunks,
                            float* __restrict__ out) {
  const int nd4 = N * DD4;
  int p = (blockIdx.x % nPairChunks) * blockDim.x + threadIdx.x;
  float acc = 0.f;
  if (p < npair) {
    const int twoSm1 = 2 * S - 1;
    int i = (int)((twoSm1 - sqrt((double)twoSm1 * twoSm1 - 8.0 * (double)p)) * 0.5);
    if (i < 0) i = 0;
    if (i > S - 2) i = S - 2;
#define BASE(ii) ((ii) * (twoSm1 - (ii)) / 2)
    while (i < S - 2 && BASE(i + 1) <= p) ++i;
    while (i > 0 && BASE(i) > p) --i;
    int j = i + 1 + (p - BASE(i));
#undef BASE
    int u0 = nodes[i], u1 = nodes[j];
    float bij = beta[u0] + beta[u1];
    size_t r0 = (size_t)u0 * DD4;
    size_t r1 = (size_t)u1 * DD4;
    float dxt[DD];
#pragma unroll
    for (int q = 0; q < DD4; ++q) {
      float4 a = x04[r0 + q];
      float4 bb = x04[r1 + q];
      dxt[q * 4 + 0] = a.x - bb.x;
      dxt[q * 4 + 1] = a.y - bb.y;
      dxt[q * 4 + 2] = a.z - bb.z;
      dxt[q * 4 + 3] = a.w - bb.w;
    }
    for (int b = 0; b < BINSN; ++b) {
      size_t bo4 = (size_t)b * nd4;
      float sdd = 0.f, sxd = 0.f, sxx = 0.f;
#pragma unroll
      for (int q = 0; q < DD4; ++q) {
        float4 a = v4[bo4 + r0 + q];
        float4 c = v4[bo4 + r1 + q];
        float d0 = a.x - c.x, d1 = a.y - c.y, d2 = a.z - c.z, d3 = a.w - c.w;
        float y0 = dxt[q * 4 + 0], y1 = dxt[q * 4 + 1];
        float y2 = dxt[q * 4 + 2], y3 = dxt[q * 4 + 3];
        sdd += d0 * d0 + d1 * d1 + d2 * d2 + d3 * d3;
        sxd += y0 * d0 + y1 * d1 + y2 * d2 + y3 * d3;
        sxx += y0 * y0 + y1 * y1 + y2 * y2 + y3 * y3;
        dxt[q * 4 + 0] = fmaf(BWF, d0, y0);
        dxt[q * 4 + 1] = fmaf(BWF, d1, y1);
        dxt[q * 4 + 2] = fmaf(BWF, d2, y2);
        dxt[q * 4 + 3] = fmaf(BWF, d3, y3);
      }
      float ndv = sqrtf(sdd);
      float inv = __fdividef(1.0f, ndv + EPSF);
      float r = sxd * inv;
      float t1 = __expf(bij + r * r - sxx);
      float lo = fmaf((float)b * BWF, ndv, r);
      float hi = fmaf((float)(b + 1) * BWF, ndv, r);
      acc += SQRTPI_HALF * inv * t1 * (fast_erff(hi) - fast_erff(lo));
    }
  }
#pragma unroll
  for (int m = 32; m >= 1; m >>= 1) acc += __shfl_xor(acc, m, 64);
  __shared__ float smem[16];
  int wid = threadIdx.x >> 6;
  if ((threadIdx.x & 63) == 0) smem[wid] = acc;
  __syncthreads();
  if (threadIdx.x == 0) {
    float tot = 0.f;
    int nw = blockDim.x >> 6;
    for (int w = 0; w < nw; ++w) tot += smem[w];
    atomicAdd(out, tot);
  }
}

__global__ void zero_out_kernel(float* __restrict__ out, int out_size) {
  int i = blockIdx.x * blockDim.x + threadIdx.x;
  if (i < out_size) out[i] = 0.f;
}

extern "C" void kernel_launch(void* const* d_in, const int* in_sizes, int n_in,
                              void* d_out, int out_size, void* d_ws, size_t ws_size,
                              hipStream_t stream) {
  const float* x0 = (const float*)d_in[0];
  const float* v = (const float*)d_in[1];
  const float* beta = (const float*)d_in[2];
  const float* times = (const float*)d_in[3];
  const int* pairs = (const int*)d_in[4];
  const int* nodes = (const int*)d_in[5];
  int N = in_sizes[2];          // 8192
  int E = in_sizes[3];          // 100000
  int S = in_sizes[5];          // 256
  float* out = (float*)d_out;
  const int ND = N * DD;

  // workspace layout (256B-aligned chunks)
  size_t off = 0;
  auto alloc = [&](size_t bytes) { size_t o = off; off = (off + bytes + 255) & ~(size_t)255; return o; };
  size_t oPh = alloc((size_t)BINSN * ND * sizeof(__half));
  size_t oPs = alloc((size_t)BINSN * S * DD * sizeof(float));
  size_t oVs = alloc((size_t)BINSN * S * DD * sizeof(float));
  size_t oBs = alloc((size_t)S * sizeof(float));
  size_t oSl = alloc((size_t)NSLOT * SLOT_STRIDE * sizeof(float));
  bool useFast = (ws_size >= off);

  if (useFast) {
    char* base = (char*)d_ws;
    __half* Ph = (__half*)(base + oPh);
    float* Ps = (float*)(base + oPs);
    float* Vs = (float*)(base + oVs);
    float* Bs = (float*)(base + oBs);
    float* slots = (float*)(base + oSl);

    int posBlocks = (ND + 255) / 256;                        // 1024
    int subBlocks = (S * DD + 255) / 256;                    // 32
    prep_kernel<<<posBlocks + subBlocks, 256, 0, stream>>>(
        x0, v, Ph, beta, nodes, Ps, Vs, Bs, N, S, posBlocks, slots);

    int nQ = (E + 3) / 4;                                    // 25000
    int evBlocks = (nQ * 32 + 255) / 256;                    // 3125
    event_kernel_h<<<evBlocks, 256, 0, stream>>>(Ph, v, beta, times, pairs,
                                                 N, E, nQ, slots);

    int ntr = (S + TS2 - 1) / TS2;                           // 8
    int nTiles = ntr * (ntr + 1) / 2;                        // 36
    integral_v10<<<nTiles * BINSN, 256, 0, stream>>>(
        (const float4*)Ps, (const float4*)Vs, Bs, S, ntr, nTiles, slots);

    finalize_kernel<<<1, 256, 0, stream>>>(slots, out, out_size);
  } else {
    zero_out_kernel<<<(out_size + 255) / 256, 256, 0, stream>>>(out, out_size);
    event_kernel_fb<<<2048, 256, 0, stream>>>(x0, v, beta, times, pairs, N, E, out);
    int npair = S * (S - 1) / 2;
    int nPairChunks = (npair + 255) / 256;
    integral_fb<<<nPairChunks, 256, 0, stream>>>(
        (const float4*)x0, (const float4*)v, beta, nodes, N, S, npair,
        nPairChunks, out);
  }
}

// Round 12
// 47.830 us; speedup vs baseline: 3.9949x; 1.0742x over previous
//
#include <hip/hip_runtime.h>
#include <hip/hip_fp16.h>
#include <math.h>

#define BINSN 50
#define DD 32
#define DD4 8
#define BWF 0.02f            // fp32 of LAST_TIME/BINS
#define EPSF 1e-6f
#define SQRTPI_HALF 0.8862269254527580f
#define TS2 32               // node tile size for integral path
#define NSLOT 256
#define SLOT_STRIDE 16       // floats; 64B apart -> no contention
#define SKIP_ARG -25.0f      // exp(arg) < 1.4e-11: cell contribution < 2.5e-5

// Branch-free erf, Abramowitz-Stegun 7.1.26, |err| <= 1.5e-7 absolute.
__device__ __forceinline__ float fast_erff(float x) {
  float ax = fabsf(x);
  float t = __fdividef(1.0f, fmaf(0.3275911f, ax, 1.0f));
  float p = t * fmaf(t, fmaf(t, fmaf(t, fmaf(t, 1.061405429f, -1.453152027f),
                                     1.421413741f), -0.284496736f), 0.254829592f);
  float y = 1.0f - p * __expf(-ax * ax);
  return copysignf(y, x);
}

__device__ __forceinline__ void block_reduce_to_slot(float acc, float* slots) {
#pragma unroll
  for (int m = 32; m >= 1; m >>= 1) acc += __shfl_xor(acc, m, 64);
  __shared__ float red[4];
  int wid = threadIdx.x >> 6;
  if ((threadIdx.x & 63) == 0) red[wid] = acc;
  __syncthreads();
  if (threadIdx.x == 0) {
    float tot = red[0] + red[1] + red[2] + red[3];
    atomicAdd(&slots[(blockIdx.x & (NSLOT - 1)) * SLOT_STRIDE], tot);
  }
}

// ---------------- Kernel 1: fused {pos->fp16 Ph} + {subset Ps/Vs/Bs} -----------
__global__ __launch_bounds__(256)
void prep_kernel(const float* __restrict__ x0, const float* __restrict__ v,
                 __half* __restrict__ Ph,
                 const float* __restrict__ beta, const int* __restrict__ nodes,
                 float* __restrict__ Ps, float* __restrict__ Vs,
                 float* __restrict__ Bs,
                 int N, int S, int posBlocks,
                 float* __restrict__ slots) {
  int tx = threadIdx.x;
  const int ND = N * DD;
  if (blockIdx.x == 0) {
    for (int o = tx; o < NSLOT * SLOT_STRIDE; o += blockDim.x) slots[o] = 0.f;
  }
  if ((int)blockIdx.x < posBlocks) {
    int idx = blockIdx.x * blockDim.x + tx;
    if (idx >= ND) return;
    float run = x0[idx];
#pragma unroll 10
    for (int b = 0; b < BINSN; ++b) {
      size_t off = (size_t)b * ND + idx;
      Ph[off] = __float2half(run);
      run = fmaf(BWF, v[off], run);
    }
  } else {
    int flat = (blockIdx.x - posBlocks) * blockDim.x + tx;  // (s,d)
    if (flat >= S * DD) return;
    int d = flat & (DD - 1);
    int s = flat >> 5;
    int node = nodes[s];
    size_t base = (size_t)node * DD + d;
    float run = x0[base];
    if (d == 0) Bs[s] = beta[node];
#pragma unroll 10
    for (int b = 0; b < BINSN; ++b) {
      size_t so = ((size_t)b * S + s) * DD + d;
      float vv = v[(size_t)b * ND + base];
      Ps[so] = run;
      Vs[so] = vv;
      run = fmaf(BWF, vv, run);
    }
  }
}

// ---------------- Kernel 2 (fused): integral tiles [0,nIntBlocks) + event blocks
// Integral blocks first (longer work starts early); event blocks backfill and
// their 4-deep independent gather chains hide under integral compute.
__global__ __launch_bounds__(256)
void work_kernel(const float4* __restrict__ Ps4,
                 const float4* __restrict__ Vs4,
                 const float* __restrict__ Bs,
                 const __half* __restrict__ Ph,
                 const float* __restrict__ v,
                 const float* __restrict__ beta,
                 const float* __restrict__ times,
                 const int* __restrict__ pairs,
                 int N, int S, int E, int nQ,
                 int nTileRows, int nTiles, int nIntBlocks,
                 float* __restrict__ slots) {
  int tx = threadIdx.x;

  if ((int)blockIdx.x < nIntBlocks) {
    // ================= integral path =================
    int tile = blockIdx.x % nTiles;
    int b = blockIdx.x / nTiles;
    int ti = 0;
    {
      int rem = tile;
      while (rem >= nTileRows - ti) { rem -= (nTileRows - ti); ++ti; }
      tile = rem;
    }
    int tj = ti + tile;

    __shared__ float sP[64][36];  // pad 36: strided j-reads -> free 2-way conflict
    __shared__ float sV[64][36];
    __shared__ float sB[64];

    {
      int row = tx >> 3, q = tx & 7;
      int g0 = ti * TS2 + row;
      if (g0 >= S) g0 = S - 1;
      size_t a0 = ((size_t)b * S + g0) * DD4 + q;
      *(float4*)&sP[row][q * 4] = Ps4[a0];
      *(float4*)&sV[row][q * 4] = Vs4[a0];
      int g1 = tj * TS2 + row;
      if (g1 >= S) g1 = S - 1;
      size_t a1 = ((size_t)b * S + g1) * DD4 + q;
      *(float4*)&sP[row + 32][q * 4] = Ps4[a1];
      *(float4*)&sV[row + 32][q * 4] = Vs4[a1];
      if (q == 0) { sB[row] = Bs[g0]; sB[row + 32] = Bs[g1]; }
    }
    __syncthreads();

    int ii = tx >> 4;
    int jj = tx & 15;

    float sdd00 = 0.f, sxd00 = 0.f, sxx00 = 0.f;
    float sdd01 = 0.f, sxd01 = 0.f, sxx01 = 0.f;
    float sdd10 = 0.f, sxd10 = 0.f, sxx10 = 0.f;
    float sdd11 = 0.f, sxd11 = 0.f, sxx11 = 0.f;

#define CELL(SDD, SXD, SXX, PA, PB, VA, VB)                                    \
    {                                                                          \
      float dx0 = PA.x - PB.x, dx1 = PA.y - PB.y;                              \
      float dx2 = PA.z - PB.z, dx3 = PA.w - PB.w;                              \
      float dv0 = VA.x - VB.x, dv1 = VA.y - VB.y;                              \
      float dv2 = VA.z - VB.z, dv3 = VA.w - VB.w;                              \
      SDD = fmaf(dv0, dv0, fmaf(dv1, dv1, fmaf(dv2, dv2, fmaf(dv3, dv3, SDD))));\
      SXD = fmaf(dx0, dv0, fmaf(dx1, dv1, fmaf(dx2, dv2, fmaf(dx3, dv3, SXD))));\
      SXX = fmaf(dx0, dx0, fmaf(dx1, dx1, fmaf(dx2, dx2, fmaf(dx3, dx3, SXX))));\
    }

#pragma unroll 4
    for (int q = 0; q < 8; ++q) {
      const float4 Pi0 = *(const float4*)&sP[ii][q * 4];
      const float4 Pi1 = *(const float4*)&sP[ii + 16][q * 4];
      const float4 Pj0 = *(const float4*)&sP[TS2 + jj][q * 4];
      const float4 Pj1 = *(const float4*)&sP[TS2 + jj + 16][q * 4];
      const float4 Vi0 = *(const float4*)&sV[ii][q * 4];
      const float4 Vi1 = *(const float4*)&sV[ii + 16][q * 4];
      const float4 Vj0 = *(const float4*)&sV[TS2 + jj][q * 4];
      const float4 Vj1 = *(const float4*)&sV[TS2 + jj + 16][q * 4];
      CELL(sdd00, sxd00, sxx00, Pi0, Pj0, Vi0, Vj0);
      CELL(sdd01, sxd01, sxx01, Pi0, Pj1, Vi0, Vj1);
      CELL(sdd10, sxd10, sxx10, Pi1, Pj0, Vi1, Vj0);
      CELL(sdd11, sxd11, sxx11, Pi1, Pj1, Vi1, Vj1);
    }
#undef CELL

    float acc = 0.f;
    const float tlo = (float)b * BWF;
    const float thi = (float)(b + 1) * BWF;

#define FIN(SDD, SXD, SXX, AOFF, COFF)                                         \
    {                                                                          \
      int li = ii + (AOFF), lj = jj + (COFF);                                  \
      int gi = ti * TS2 + li, gj = tj * TS2 + lj;                              \
      if (gi < gj && gj < S) {                                                 \
        float ndv = sqrtf(SDD);                                                \
        float inv = __fdividef(1.0f, ndv + EPSF);                              \
        float r = SXD * inv;                                                   \
        float bij = sB[li] + sB[TS2 + lj];                                     \
        float arg = bij + fmaf(r, r, -(SXX));                                  \
        if (arg > SKIP_ARG) {                                                  \
          float t1 = __expf(arg);                                              \
          float lo = fmaf(tlo, ndv, r);                                        \
          float hi = fmaf(thi, ndv, r);                                        \
          acc += SQRTPI_HALF * inv * t1 * (fast_erff(hi) - fast_erff(lo));     \
        }                                                                      \
      }                                                                        \
    }

    FIN(sdd00, sxd00, sxx00, 0, 0);
    FIN(sdd01, sxd01, sxx01, 0, 16);
    FIN(sdd10, sxd10, sxx10, 16, 0);
    FIN(sdd11, sxd11, sxx11, 16, 16);
#undef FIN

    block_reduce_to_slot(acc, slots);
  } else {
    // ================= event path: FOUR events per 32-lane slot =================
    const int ND = N * DD;
    const int lane = tx & 31;
    int ebid = blockIdx.x - nIntBlocks;
    int slotId = (int)((ebid * blockDim.x + tx) >> 5);
    float acc = 0.f;

#define EV_BODY(EIDX)                                                          \
    {                                                                          \
      float t = times[EIDX];                                                   \
      int p0 = pairs[EIDX];                                                    \
      int p1 = pairs[E + (EIDX)];                                              \
      float fb = floorf(t / BWF);                                              \
      float res = fmaf(-BWF, fb, t);                                           \
      int b = (int)fb;                                                         \
      b = b < 0 ? 0 : (b > BINSN - 1 ? BINSN - 1 : b);                         \
      size_t o0 = (size_t)p0 * DD + lane;                                      \
      size_t o1 = (size_t)p1 * DD + lane;                                      \
      size_t bo = (size_t)b * ND;                                              \
      float dP = __half2float(Ph[bo + o0]) - __half2float(Ph[bo + o1]);        \
      float dx = dP + res * (v[bo + o0] - v[bo + o1]);                         \
      float s = dx * dx;                                                       \
      _Pragma("unroll")                                                        \
      for (int m = 16; m >= 1; m >>= 1) s += __shfl_xor(s, m, 64);             \
      if (lane == 0) acc += s - beta[p0] - beta[p1];                           \
    }

    int e0 = slotId;
    int e1 = slotId + nQ;
    int e2 = slotId + 2 * nQ;
    int e3 = slotId + 3 * nQ;
    if (e0 < E) EV_BODY(e0);
    if (e1 < E) EV_BODY(e1);
    if (e2 < E) EV_BODY(e2);
    if (e3 < E) EV_BODY(e3);
#undef EV_BODY

    block_reduce_to_slot(acc, slots);
  }
}

// ---------------- finalize: sum slots -> out[0] ----------------
__global__ void finalize_kernel(const float* __restrict__ slots,
                                float* __restrict__ out, int out_size) {
  float a = slots[threadIdx.x * SLOT_STRIDE];
#pragma unroll
  for (int m = 32; m >= 1; m >>= 1) a += __shfl_xor(a, m, 64);
  __shared__ float red[4];
  int wid = threadIdx.x >> 6;
  if ((threadIdx.x & 63) == 0) red[wid] = a;
  __syncthreads();
  if (threadIdx.x == 0) out[0] = red[0] + red[1] + red[2] + red[3];
  if (threadIdx.x > 0 && threadIdx.x < out_size) out[threadIdx.x] = 0.f;
}

// ---------------- Fallback kernels (workspace too small) ----------------
__global__ void event_kernel_fb(const float* __restrict__ x0,
                                const float* __restrict__ v,
                                const float* __restrict__ beta,
                                const float* __restrict__ times,
                                const int* __restrict__ pairs,
                                int N, int E, float* __restrict__ out) {
  const int ND = N * DD;
  const int lane = threadIdx.x & 31;
  int slot = (blockIdx.x * blockDim.x + threadIdx.x) >> 5;
  const int nslots = (gridDim.x * blockDim.x) >> 5;
  float acc = 0.f;
  for (int e = slot; e < E; e += nslots) {
    float t = times[e];
    int p0 = pairs[e];
    int p1 = pairs[E + e];
    float fb = floorf(t / BWF);
    float res = fmaf(-BWF, fb, t);
    int b = (int)fb;
    b = b < 0 ? 0 : (b > BINSN - 1 ? BINSN - 1 : b);
    size_t o0 = (size_t)p0 * DD + lane;
    size_t o1 = (size_t)p1 * DD + lane;
    size_t bo = (size_t)b * ND;
    float c0 = 0.f, c1 = 0.f;
    for (int k = 0; k < b; ++k) {
      size_t ko = (size_t)k * ND;
      c0 += v[ko + o0];
      c1 += v[ko + o1];
    }
    float dx = (x0[o0] - x0[o1]) + BWF * (c0 - c1) + res * (v[bo + o0] - v[bo + o1]);
    float s = dx * dx;
#pragma unroll
    for (int m = 16; m >= 1; m >>= 1) s += __shfl_xor(s, m, 64);
    if (lane == 0) acc += s - beta[p0] - beta[p1];
  }
#pragma unroll
  for (int m = 32; m >= 1; m >>= 1) acc += __shfl_xor(acc, m, 64);
  __shared__ float smem[16];
  int wid = threadIdx.x >> 6;
  if ((threadIdx.x & 63) == 0) smem[wid] = acc;
  __syncthreads();
  if (threadIdx.x == 0) {
    float tot = 0.f;
    int nw = blockDim.x >> 6;
    for (int w = 0; w < nw; ++w) tot += smem[w];
    atomicAdd(out, tot);
  }
}

__global__ void integral_fb(const float4* __restrict__ x04,
                            const float4* __restrict__ v4,
                            const float* __restrict__ beta,
                            const int* __restrict__ nodes,
                            int N, int S, int npair, int nPairChunks,
                            float* __restrict__ out) {
  const int nd4 = N * DD4;
  int p = (blockIdx.x % nPairChunks) * blockDim.x + threadIdx.x;
  float acc = 0.f;
  if (p < npair) {
    const int twoSm1 = 2 * S - 1;
    int i = (int)((twoSm1 - sqrt((double)twoSm1 * twoSm1 - 8.0 * (double)p)) * 0.5);
    if (i < 0) i = 0;
    if (i > S - 2) i = S - 2;
#define BASE(ii) ((ii) * (twoSm1 - (ii)) / 2)
    while (i < S - 2 && BASE(i + 1) <= p) ++i;
    while (i > 0 && BASE(i) > p) --i;
    int j = i + 1 + (p - BASE(i));
#undef BASE
    int u0 = nodes[i], u1 = nodes[j];
    float bij = beta[u0] + beta[u1];
    size_t r0 = (size_t)u0 * DD4;
    size_t r1 = (size_t)u1 * DD4;
    float dxt[DD];
#pragma unroll
    for (int q = 0; q < DD4; ++q) {
      float4 a = x04[r0 + q];
      float4 bb = x04[r1 + q];
      dxt[q * 4 + 0] = a.x - bb.x;
      dxt[q * 4 + 1] = a.y - bb.y;
      dxt[q * 4 + 2] = a.z - bb.z;
      dxt[q * 4 + 3] = a.w - bb.w;
    }
    for (int b = 0; b < BINSN; ++b) {
      size_t bo4 = (size_t)b * nd4;
      float sdd = 0.f, sxd = 0.f, sxx = 0.f;
#pragma unroll
      for (int q = 0; q < DD4; ++q) {
        float4 a = v4[bo4 + r0 + q];
        float4 c = v4[bo4 + r1 + q];
        float d0 = a.x - c.x, d1 = a.y - c.y, d2 = a.z - c.z, d3 = a.w - c.w;
        float y0 = dxt[q * 4 + 0], y1 = dxt[q * 4 + 1];
        float y2 = dxt[q * 4 + 2], y3 = dxt[q * 4 + 3];
        sdd += d0 * d0 + d1 * d1 + d2 * d2 + d3 * d3;
        sxd += y0 * d0 + y1 * d1 + y2 * d2 + y3 * d3;
        sxx += y0 * y0 + y1 * y1 + y2 * y2 + y3 * y3;
        dxt[q * 4 + 0] = fmaf(BWF, d0, y0);
        dxt[q * 4 + 1] = fmaf(BWF, d1, y1);
        dxt[q * 4 + 2] = fmaf(BWF, d2, y2);
        dxt[q * 4 + 3] = fmaf(BWF, d3, y3);
      }
      float ndv = sqrtf(sdd);
      float inv = __fdividef(1.0f, ndv + EPSF);
      float r = sxd * inv;
      float t1 = __expf(bij + r * r - sxx);
      float lo = fmaf((float)b * BWF, ndv, r);
      float hi = fmaf((float)(b + 1) * BWF, ndv, r);
      acc += SQRTPI_HALF * inv * t1 * (fast_erff(hi) - fast_erff(lo));
    }
  }
#pragma unroll
  for (int m = 32; m >= 1; m >>= 1) acc += __shfl_xor(acc, m, 64);
  __shared__ float smem[16];
  int wid = threadIdx.x >> 6;
  if ((threadIdx.x & 63) == 0) smem[wid] = acc;
  __syncthreads();
  if (threadIdx.x == 0) {
    float tot = 0.f;
    int nw = blockDim.x >> 6;
    for (int w = 0; w < nw; ++w) tot += smem[w];
    atomicAdd(out, tot);
  }
}

__global__ void zero_out_kernel(float* __restrict__ out, int out_size) {
  int i = blockIdx.x * blockDim.x + threadIdx.x;
  if (i < out_size) out[i] = 0.f;
}

extern "C" void kernel_launch(void* const* d_in, const int* in_sizes, int n_in,
                              void* d_out, int out_size, void* d_ws, size_t ws_size,
                              hipStream_t stream) {
  const float* x0 = (const float*)d_in[0];
  const float* v = (const float*)d_in[1];
  const float* beta = (const float*)d_in[2];
  const float* times = (const float*)d_in[3];
  const int* pairs = (const int*)d_in[4];
  const int* nodes = (const int*)d_in[5];
  int N = in_sizes[2];          // 8192
  int E = in_sizes[3];          // 100000
  int S = in_sizes[5];          // 256
  float* out = (float*)d_out;
  const int ND = N * DD;

  // workspace layout (256B-aligned chunks)
  size_t off = 0;
  auto alloc = [&](size_t bytes) { size_t o = off; off = (off + bytes + 255) & ~(size_t)255; return o; };
  size_t oPh = alloc((size_t)BINSN * ND * sizeof(__half));
  size_t oPs = alloc((size_t)BINSN * S * DD * sizeof(float));
  size_t oVs = alloc((size_t)BINSN * S * DD * sizeof(float));
  size_t oBs = alloc((size_t)S * sizeof(float));
  size_t oSl = alloc((size_t)NSLOT * SLOT_STRIDE * sizeof(float));
  bool useFast = (ws_size >= off);

  if (useFast) {
    char* base = (char*)d_ws;
    __half* Ph = (__half*)(base + oPh);
    float* Ps = (float*)(base + oPs);
    float* Vs = (float*)(base + oVs);
    float* Bs = (float*)(base + oBs);
    float* slots = (float*)(base + oSl);

    int posBlocks = (ND + 255) / 256;                        // 1024
    int subBlocks = (S * DD + 255) / 256;                    // 32
    prep_kernel<<<posBlocks + subBlocks, 256, 0, stream>>>(
        x0, v, Ph, beta, nodes, Ps, Vs, Bs, N, S, posBlocks, slots);

    int ntr = (S + TS2 - 1) / TS2;                           // 8
    int nTiles = ntr * (ntr + 1) / 2;                        // 36
    int nIntBlocks = nTiles * BINSN;                         // 1800
    int nQ = (E + 3) / 4;                                    // 25000
    int evBlocks = (nQ * 32 + 255) / 256;                    // 3125
    work_kernel<<<nIntBlocks + evBlocks, 256, 0, stream>>>(
        (const float4*)Ps, (const float4*)Vs, Bs, Ph, v, beta, times, pairs,
        N, S, E, nQ, ntr, nTiles, nIntBlocks, slots);

    finalize_kernel<<<1, 256, 0, stream>>>(slots, out, out_size);
  } else {
    zero_out_kernel<<<(out_size + 255) / 256, 256, 0, stream>>>(out, out_size);
    event_kernel_fb<<<2048, 256, 0, stream>>>(x0, v, beta, times, pairs, N, E, out);
    int npair = S * (S - 1) / 2;
    int nPairChunks = (npair + 255) / 256;
    integral_fb<<<nPairChunks, 256, 0, stream>>>(
        (const float4*)x0, (const float4*)v, beta, nodes, N, S, npair,
        nPairChunks, out);
  }
}

// Round 13
// 45.173 us; speedup vs baseline: 4.2299x; 1.0588x over previous
//
#include <hip/hip_runtime.h>
#include <hip/hip_fp16.h>
#include <math.h>

#define BINSN 50
#define DD 32
#define DD4 8
#define BWF 0.02f            // fp32 of LAST_TIME/BINS
#define EPSF 1e-6f
#define SQRTPI_HALF 0.8862269254527580f
#define TS2 32               // node tile size for integral path
#define NSLOT 256
#define SLOT_STRIDE 16       // floats; 64B apart -> no contention
#define SKIP_ARG -25.0f      // exp(arg) < 1.4e-11: cell contribution < 2.5e-5
#define EV_PER_SLOT 8

// Branch-free erf, Abramowitz-Stegun 7.1.26, |err| <= 1.5e-7 absolute.
__device__ __forceinline__ float fast_erff(float x) {
  float ax = fabsf(x);
  float t = __fdividef(1.0f, fmaf(0.3275911f, ax, 1.0f));
  float p = t * fmaf(t, fmaf(t, fmaf(t, fmaf(t, 1.061405429f, -1.453152027f),
                                     1.421413741f), -0.284496736f), 0.254829592f);
  float y = 1.0f - p * __expf(-ax * ax);
  return copysignf(y, x);
}

__device__ __forceinline__ void block_reduce_to_slot(float acc, float* slots) {
#pragma unroll
  for (int m = 32; m >= 1; m >>= 1) acc += __shfl_xor(acc, m, 64);
  __shared__ float red[4];
  int wid = threadIdx.x >> 6;
  if ((threadIdx.x & 63) == 0) red[wid] = acc;
  __syncthreads();
  if (threadIdx.x == 0) {
    float tot = red[0] + red[1] + red[2] + red[3];
    atomicAdd(&slots[(blockIdx.x & (NSLOT - 1)) * SLOT_STRIDE], tot);
  }
}

// ---------------- Kernel 1: fused {pos->fp16 Ph} + {subset Ps/Vs/Bs} -----------
__global__ __launch_bounds__(256)
void prep_kernel(const float* __restrict__ x0, const float* __restrict__ v,
                 __half* __restrict__ Ph,
                 const float* __restrict__ beta, const int* __restrict__ nodes,
                 float* __restrict__ Ps, float* __restrict__ Vs,
                 float* __restrict__ Bs,
                 int N, int S, int posBlocks,
                 float* __restrict__ slots) {
  int tx = threadIdx.x;
  const int ND = N * DD;
  if (blockIdx.x == 0) {
    for (int o = tx; o < NSLOT * SLOT_STRIDE; o += blockDim.x) slots[o] = 0.f;
  }
  if ((int)blockIdx.x < posBlocks) {
    int idx = blockIdx.x * blockDim.x + tx;
    if (idx >= ND) return;
    float run = x0[idx];
#pragma unroll 10
    for (int b = 0; b < BINSN; ++b) {
      size_t off = (size_t)b * ND + idx;
      Ph[off] = __float2half(run);
      run = fmaf(BWF, v[off], run);
    }
  } else {
    int flat = (blockIdx.x - posBlocks) * blockDim.x + tx;  // (s,d)
    if (flat >= S * DD) return;
    int d = flat & (DD - 1);
    int s = flat >> 5;
    int node = nodes[s];
    size_t base = (size_t)node * DD + d;
    float run = x0[base];
    if (d == 0) Bs[s] = beta[node];
#pragma unroll 10
    for (int b = 0; b < BINSN; ++b) {
      size_t so = ((size_t)b * S + s) * DD + d;
      float vv = v[(size_t)b * ND + base];
      Ps[so] = run;
      Vs[so] = vv;
      run = fmaf(BWF, vv, run);
    }
  }
}

// ---------------- Kernel 2 (fused): integral tiles + event blocks --------------
// Event path: EIGHT events per slot; all 32 independent gathers issued BEFORE
// any reduce (issue-early / reduce-late) -> 8x the memory-level parallelism of
// a per-event loop whose shfl-reduce serializes the chains.
__global__ __launch_bounds__(256)
void work_kernel(const float4* __restrict__ Ps4,
                 const float4* __restrict__ Vs4,
                 const float* __restrict__ Bs,
                 const __half* __restrict__ Ph,
                 const float* __restrict__ v,
                 const float* __restrict__ beta,
                 const float* __restrict__ times,
                 const int* __restrict__ pairs,
                 int N, int S, int E, int nOct,
                 int nTileRows, int nTiles, int nIntBlocks,
                 float* __restrict__ slots) {
  int tx = threadIdx.x;

  if ((int)blockIdx.x < nIntBlocks) {
    // ================= integral path =================
    int tile = blockIdx.x % nTiles;
    int b = blockIdx.x / nTiles;
    int ti = 0;
    {
      int rem = tile;
      while (rem >= nTileRows - ti) { rem -= (nTileRows - ti); ++ti; }
      tile = rem;
    }
    int tj = ti + tile;

    __shared__ float sP[64][36];  // pad 36: strided j-reads -> free 2-way conflict
    __shared__ float sV[64][36];
    __shared__ float sB[64];

    {
      int row = tx >> 3, q = tx & 7;
      int g0 = ti * TS2 + row;
      if (g0 >= S) g0 = S - 1;
      size_t a0 = ((size_t)b * S + g0) * DD4 + q;
      *(float4*)&sP[row][q * 4] = Ps4[a0];
      *(float4*)&sV[row][q * 4] = Vs4[a0];
      int g1 = tj * TS2 + row;
      if (g1 >= S) g1 = S - 1;
      size_t a1 = ((size_t)b * S + g1) * DD4 + q;
      *(float4*)&sP[row + 32][q * 4] = Ps4[a1];
      *(float4*)&sV[row + 32][q * 4] = Vs4[a1];
      if (q == 0) { sB[row] = Bs[g0]; sB[row + 32] = Bs[g1]; }
    }
    __syncthreads();

    int ii = tx >> 4;
    int jj = tx & 15;

    float sdd00 = 0.f, sxd00 = 0.f, sxx00 = 0.f;
    float sdd01 = 0.f, sxd01 = 0.f, sxx01 = 0.f;
    float sdd10 = 0.f, sxd10 = 0.f, sxx10 = 0.f;
    float sdd11 = 0.f, sxd11 = 0.f, sxx11 = 0.f;

#define CELL(SDD, SXD, SXX, PA, PB, VA, VB)                                    \
    {                                                                          \
      float dx0 = PA.x - PB.x, dx1 = PA.y - PB.y;                              \
      float dx2 = PA.z - PB.z, dx3 = PA.w - PB.w;                              \
      float dv0 = VA.x - VB.x, dv1 = VA.y - VB.y;                              \
      float dv2 = VA.z - VB.z, dv3 = VA.w - VB.w;                              \
      SDD = fmaf(dv0, dv0, fmaf(dv1, dv1, fmaf(dv2, dv2, fmaf(dv3, dv3, SDD))));\
      SXD = fmaf(dx0, dv0, fmaf(dx1, dv1, fmaf(dx2, dv2, fmaf(dx3, dv3, SXD))));\
      SXX = fmaf(dx0, dx0, fmaf(dx1, dx1, fmaf(dx2, dx2, fmaf(dx3, dx3, SXX))));\
    }

#pragma unroll 4
    for (int q = 0; q < 8; ++q) {
      const float4 Pi0 = *(const float4*)&sP[ii][q * 4];
      const float4 Pi1 = *(const float4*)&sP[ii + 16][q * 4];
      const float4 Pj0 = *(const float4*)&sP[TS2 + jj][q * 4];
      const float4 Pj1 = *(const float4*)&sP[TS2 + jj + 16][q * 4];
      const float4 Vi0 = *(const float4*)&sV[ii][q * 4];
      const float4 Vi1 = *(const float4*)&sV[ii + 16][q * 4];
      const float4 Vj0 = *(const float4*)&sV[TS2 + jj][q * 4];
      const float4 Vj1 = *(const float4*)&sV[TS2 + jj + 16][q * 4];
      CELL(sdd00, sxd00, sxx00, Pi0, Pj0, Vi0, Vj0);
      CELL(sdd01, sxd01, sxx01, Pi0, Pj1, Vi0, Vj1);
      CELL(sdd10, sxd10, sxx10, Pi1, Pj0, Vi1, Vj0);
      CELL(sdd11, sxd11, sxx11, Pi1, Pj1, Vi1, Vj1);
    }
#undef CELL

    float acc = 0.f;
    const float tlo = (float)b * BWF;
    const float thi = (float)(b + 1) * BWF;

#define FIN(SDD, SXD, SXX, AOFF, COFF)                                         \
    {                                                                          \
      int li = ii + (AOFF), lj = jj + (COFF);                                  \
      int gi = ti * TS2 + li, gj = tj * TS2 + lj;                              \
      if (gi < gj && gj < S) {                                                 \
        float ndv = sqrtf(SDD);                                                \
        float inv = __fdividef(1.0f, ndv + EPSF);                              \
        float r = SXD * inv;                                                   \
        float bij = sB[li] + sB[TS2 + lj];                                     \
        float arg = bij + fmaf(r, r, -(SXX));                                  \
        if (arg > SKIP_ARG) {                                                  \
          float t1 = __expf(arg);                                              \
          float lo = fmaf(tlo, ndv, r);                                        \
          float hi = fmaf(thi, ndv, r);                                        \
          acc += SQRTPI_HALF * inv * t1 * (fast_erff(hi) - fast_erff(lo));     \
        }                                                                      \
      }                                                                        \
    }

    FIN(sdd00, sxd00, sxx00, 0, 0);
    FIN(sdd01, sxd01, sxx01, 0, 16);
    FIN(sdd10, sxd10, sxx10, 16, 0);
    FIN(sdd11, sxd11, sxx11, 16, 16);
#undef FIN

    block_reduce_to_slot(acc, slots);
  } else {
    // ============ event path: 8 events/slot, issue-early reduce-late ============
    const int ND = N * DD;
    const int lane = tx & 31;
    int ebid = blockIdx.x - nIntBlocks;
    int slotId = (int)((ebid * blockDim.x + tx) >> 5);
    bool slotOk = (slotId < nOct);

    float ph0[EV_PER_SLOT], ph1[EV_PER_SLOT], va[EV_PER_SLOT], vb[EV_PER_SLOT];
    float resv[EV_PER_SLOT];
    int pp0[EV_PER_SLOT], pp1[EV_PER_SLOT];
    bool val[EV_PER_SLOT];

#pragma unroll
    for (int k = 0; k < EV_PER_SLOT; ++k) {
      int e = slotId + k * nOct;
      val[k] = slotOk && (e < E);
      int ee = val[k] ? e : 0;
      float t = times[ee];
      pp0[k] = pairs[ee];
      pp1[k] = pairs[E + ee];
      float fb = floorf(t / BWF);
      resv[k] = fmaf(-BWF, fb, t);
      int b = (int)fb;
      b = b < 0 ? 0 : (b > BINSN - 1 ? BINSN - 1 : b);
      size_t bo = (size_t)b * ND;
      size_t o0 = bo + (size_t)pp0[k] * DD + lane;
      size_t o1 = bo + (size_t)pp1[k] * DD + lane;
      ph0[k] = __half2float(Ph[o0]);
      ph1[k] = __half2float(Ph[o1]);
      va[k] = v[o0];
      vb[k] = v[o1];
    }

    float acc = 0.f;
#pragma unroll
    for (int k = 0; k < EV_PER_SLOT; ++k) {
      float dx = (ph0[k] - ph1[k]) + resv[k] * (va[k] - vb[k]);
      float s = dx * dx;
#pragma unroll
      for (int m = 16; m >= 1; m >>= 1) s += __shfl_xor(s, m, 64);
      if (lane == 0 && val[k]) acc += s - beta[pp0[k]] - beta[pp1[k]];
    }

    block_reduce_to_slot(acc, slots);
  }
}

// ---------------- finalize: sum slots -> out[0] ----------------
__global__ void finalize_kernel(const float* __restrict__ slots,
                                float* __restrict__ out, int out_size) {
  float a = slots[threadIdx.x * SLOT_STRIDE];
#pragma unroll
  for (int m = 32; m >= 1; m >>= 1) a += __shfl_xor(a, m, 64);
  __shared__ float red[4];
  int wid = threadIdx.x >> 6;
  if ((threadIdx.x & 63) == 0) red[wid] = a;
  __syncthreads();
  if (threadIdx.x == 0) out[0] = red[0] + red[1] + red[2] + red[3];
  if (threadIdx.x > 0 && threadIdx.x < out_size) out[threadIdx.x] = 0.f;
}

// ---------------- Fallback kernels (workspace too small) ----------------
__global__ void event_kernel_fb(const float* __restrict__ x0,
                                const float* __restrict__ v,
                                const float* __restrict__ beta,
                                const float* __restrict__ times,
                                const int* __restrict__ pairs,
                                int N, int E, float* __restrict__ out) {
  const int ND = N * DD;
  const int lane = threadIdx.x & 31;
  int slot = (blockIdx.x * blockDim.x + threadIdx.x) >> 5;
  const int nslots = (gridDim.x * blockDim.x) >> 5;
  float acc = 0.f;
  for (int e = slot; e < E; e += nslots) {
    float t = times[e];
    int p0 = pairs[e];
    int p1 = pairs[E + e];
    float fb = floorf(t / BWF);
    float res = fmaf(-BWF, fb, t);
    int b = (int)fb;
    b = b < 0 ? 0 : (b > BINSN - 1 ? BINSN - 1 : b);
    size_t o0 = (size_t)p0 * DD + lane;
    size_t o1 = (size_t)p1 * DD + lane;
    size_t bo = (size_t)b * ND;
    float c0 = 0.f, c1 = 0.f;
    for (int k = 0; k < b; ++k) {
      size_t ko = (size_t)k * ND;
      c0 += v[ko + o0];
      c1 += v[ko + o1];
    }
    float dx = (x0[o0] - x0[o1]) + BWF * (c0 - c1) + res * (v[bo + o0] - v[bo + o1]);
    float s = dx * dx;
#pragma unroll
    for (int m = 16; m >= 1; m >>= 1) s += __shfl_xor(s, m, 64);
    if (lane == 0) acc += s - beta[p0] - beta[p1];
  }
#pragma unroll
  for (int m = 32; m >= 1; m >>= 1) acc += __shfl_xor(acc, m, 64);
  __shared__ float smem[16];
  int wid = threadIdx.x >> 6;
  if ((threadIdx.x & 63) == 0) smem[wid] = acc;
  __syncthreads();
  if (threadIdx.x == 0) {
    float tot = 0.f;
    int nw = blockDim.x >> 6;
    for (int w = 0; w < nw; ++w) tot += smem[w];
    atomicAdd(out, tot);
  }
}

__global__ void integral_fb(const float4* __restrict__ x04,
                            const float4* __restrict__ v4,
                            const float* __restrict__ beta,
                            const int* __restrict__ nodes,
                            int N, int S, int npair, int nPairChunks,
                            float* __restrict__ out) {
  const int nd4 = N * DD4;
  int p = (blockIdx.x % nPairChunks) * blockDim.x + threadIdx.x;
  float acc = 0.f;
  if (p < npair) {
    const int twoSm1 = 2 * S - 1;
    int i = (int)((twoSm1 - sqrt((double)twoSm1 * twoSm1 - 8.0 * (double)p)) * 0.5);
    if (i < 0) i = 0;
    if (i > S - 2) i = S - 2;
#define BASE(ii) ((ii) * (twoSm1 - (ii)) / 2)
    while (i < S - 2 && BASE(i + 1) <= p) ++i;
    while (i > 0 && BASE(i) > p) --i;
    int j = i + 1 + (p - BASE(i));
#undef BASE
    int u0 = nodes[i], u1 = nodes[j];
    float bij = beta[u0] + beta[u1];
    size_t r0 = (size_t)u0 * DD4;
    size_t r1 = (size_t)u1 * DD4;
    float dxt[DD];
#pragma unroll
    for (int q = 0; q < DD4; ++q) {
      float4 a = x04[r0 + q];
      float4 bb = x04[r1 + q];
      dxt[q * 4 + 0] = a.x - bb.x;
      dxt[q * 4 + 1] = a.y - bb.y;
      dxt[q * 4 + 2] = a.z - bb.z;
      dxt[q * 4 + 3] = a.w - bb.w;
    }
    for (int b = 0; b < BINSN; ++b) {
      size_t bo4 = (size_t)b * nd4;
      float sdd = 0.f, sxd = 0.f, sxx = 0.f;
#pragma unroll
      for (int q = 0; q < DD4; ++q) {
        float4 a = v4[bo4 + r0 + q];
        float4 c = v4[bo4 + r1 + q];
        float d0 = a.x - c.x, d1 = a.y - c.y, d2 = a.z - c.z, d3 = a.w - c.w;
        float y0 = dxt[q * 4 + 0], y1 = dxt[q * 4 + 1];
        float y2 = dxt[q * 4 + 2], y3 = dxt[q * 4 + 3];
        sdd += d0 * d0 + d1 * d1 + d2 * d2 + d3 * d3;
        sxd += y0 * d0 + y1 * d1 + y2 * d2 + y3 * d3;
        sxx += y0 * y0 + y1 * y1 + y2 * y2 + y3 * y3;
        dxt[q * 4 + 0] = fmaf(BWF, d0, y0);
        dxt[q * 4 + 1] = fmaf(BWF, d1, y1);
        dxt[q * 4 + 2] = fmaf(BWF, d2, y2);
        dxt[q * 4 + 3] = fmaf(BWF, d3, y3);
      }
      float ndv = sqrtf(sdd);
      float inv = __fdividef(1.0f, ndv + EPSF);
      float r = sxd * inv;
      float t1 = __expf(bij + r * r - sxx);
      float lo = fmaf((float)b * BWF, ndv, r);
      float hi = fmaf((float)(b + 1) * BWF, ndv, r);
      acc += SQRTPI_HALF * inv * t1 * (fast_erff(hi) - fast_erff(lo));
    }
  }
#pragma unroll
  for (int m = 32; m >= 1; m >>= 1) acc += __shfl_xor(acc, m, 64);
  __shared__ float smem[16];
  int wid = threadIdx.x >> 6;
  if ((threadIdx.x & 63) == 0) smem[wid] = acc;
  __syncthreads();
  if (threadIdx.x == 0) {
    float tot = 0.f;
    int nw = blockDim.x >> 6;
    for (int w = 0; w < nw; ++w) tot += smem[w];
    atomicAdd(out, tot);
  }
}

__global__ void zero_out_kernel(float* __restrict__ out, int out_size) {
  int i = blockIdx.x * blockDim.x + threadIdx.x;
  if (i < out_size) out[i] = 0.f;
}

extern "C" void kernel_launch(void* const* d_in, const int* in_sizes, int n_in,
                              void* d_out, int out_size, void* d_ws, size_t ws_size,
                              hipStream_t stream) {
  const float* x0 = (const float*)d_in[0];
  const float* v = (const float*)d_in[1];
  const float* beta = (const float*)d_in[2];
  const float* times = (const float*)d_in[3];
  const int* pairs = (const int*)d_in[4];
  const int* nodes = (const int*)d_in[5];
  int N = in_sizes[2];          // 8192
  int E = in_sizes[3];          // 100000
  int S = in_sizes[5];          // 256
  float* out = (float*)d_out;
  const int ND = N * DD;

  // workspace layout (256B-aligned chunks)
  size_t off = 0;
  auto alloc = [&](size_t bytes) { size_t o = off; off = (off + bytes + 255) & ~(size_t)255; return o; };
  size_t oPh = alloc((size_t)BINSN * ND * sizeof(__half));
  size_t oPs = alloc((size_t)BINSN * S * DD * sizeof(float));
  size_t oVs = alloc((size_t)BINSN * S * DD * sizeof(float));
  size_t oBs = alloc((size_t)S * sizeof(float));
  size_t oSl = alloc((size_t)NSLOT * SLOT_STRIDE * sizeof(float));
  bool useFast = (ws_size >= off);

  if (useFast) {
    char* base = (char*)d_ws;
    __half* Ph = (__half*)(base + oPh);
    float* Ps = (float*)(base + oPs);
    float* Vs = (float*)(base + oVs);
    float* Bs = (float*)(base + oBs);
    float* slots = (float*)(base + oSl);

    int posBlocks = (ND + 255) / 256;                        // 1024
    int subBlocks = (S * DD + 255) / 256;                    // 32
    prep_kernel<<<posBlocks + subBlocks, 256, 0, stream>>>(
        x0, v, Ph, beta, nodes, Ps, Vs, Bs, N, S, posBlocks, slots);

    int ntr = (S + TS2 - 1) / TS2;                           // 8
    int nTiles = ntr * (ntr + 1) / 2;                        // 36
    int nIntBlocks = nTiles * BINSN;                         // 1800
    int nOct = (E + EV_PER_SLOT - 1) / EV_PER_SLOT;          // 12500
    int evBlocks = (nOct * 32 + 255) / 256;                  // 1563
    work_kernel<<<nIntBlocks + evBlocks, 256, 0, stream>>>(
        (const float4*)Ps, (const float4*)Vs, Bs, Ph, v, beta, times, pairs,
        N, S, E, nOct, ntr, nTiles, nIntBlocks, slots);

    finalize_kernel<<<1, 256, 0, stream>>>(slots, out, out_size);
  } else {
    zero_out_kernel<<<(out_size + 255) / 256, 256, 0, stream>>>(out, out_size);
    event_kernel_fb<<<2048, 256, 0, stream>>>(x0, v, beta, times, pairs, N, E, out);
    int npair = S * (S - 1) / 2;
    int nPairChunks = (npair + 255) / 256;
    integral_fb<<<nPairChunks, 256, 0, stream>>>(
        (const float4*)x0, (const float4*)v, beta, nodes, N, S, npair,
        nPairChunks, out);
  }
}